// Round 4
// baseline (503.311 us; speedup 1.0000x reference)
//
#include <hip/hip_runtime.h>
#include <hip/hip_bf16.h>
#include <math.h>

#define DM 1024   // d_model
#define DI 2048   // d_inner
#define DS 16     // d_state
#define DC 4      // d_conv
#define DR 64     // dt_rank
#define NB 4      // batch
#define SL 2048   // seqlen
#define BL (NB * SL)        // 8192 rows
#define DXP (DR + 2 * DS)   // 96
#define NC 32               // scan chunks
#define CL (SL / NC)        // 64 steps per chunk

typedef __hip_bfloat16 bf16;
typedef __attribute__((ext_vector_type(8))) short short8;
typedef __attribute__((ext_vector_type(4))) float floatx4;
typedef unsigned int u32;

__device__ __forceinline__ float to_f(float v) { return v; }
__device__ __forceinline__ float to_f(bf16 v) { return __bfloat162float(v); }
template <typename T> __device__ __forceinline__ T from_f(float v);
template <> __device__ __forceinline__ float from_f<float>(float v) { return v; }
template <> __device__ __forceinline__ bf16 from_f<bf16>(float v) { return __float2bfloat16(v); }

__device__ __forceinline__ float bfbits2f(unsigned short u) {
  u32 b = ((u32)u) << 16;
  return __builtin_bit_cast(float, b);
}
__device__ __forceinline__ short f2bfbits(float v) {
  bf16 b = __float2bfloat16(v);
  return __builtin_bit_cast(short, b);
}
// fast silu: x * rcp(1+e^-x)  (v_rcp_f32, ~1 ulp — fine for bf16 outputs)
__device__ __forceinline__ float fsilu(float v) {
  return v * __builtin_amdgcn_rcpf(1.f + __expf(-v));
}

// async global->LDS, 16B per lane. LDS dest = wave-uniform base + lane*16.
__device__ __forceinline__ void gload16(const ushort* g, ushort* l) {
  __builtin_amdgcn_global_load_lds((const __attribute__((address_space(1))) void*)g,
                                   (__attribute__((address_space(3))) void*)l,
                                   16, 0, 0);
}

__device__ __forceinline__ void vmw2() { asm volatile("s_waitcnt vmcnt(2)" ::: "memory"); }
__device__ __forceinline__ void vmw0() { asm volatile("s_waitcnt vmcnt(0)" ::: "memory"); }
// raw barrier (NO implicit vmcnt drain) with compiler-only memory fences so
// LDS reads/stages can't migrate across phases.
__device__ __forceinline__ void barx() {
  asm volatile("" ::: "memory");
  __builtin_amdgcn_s_barrier();
  asm volatile("" ::: "memory");
}

// ---------------- fp32 -> bf16 conversion ----------------
__global__ __launch_bounds__(256) void f2b_k(const float* __restrict__ src,
                                             bf16* __restrict__ dst, int n) {
  int i = blockIdx.x * 256 + threadIdx.x;
  if (i < n) dst[i] = from_f<bf16>(src[i]);
}

// ---------------- RMSNorm (bf16 out) ----------------
__global__ __launch_bounds__(256) void rmsnorm_k(const float* __restrict__ x,
                                                 const float* __restrict__ w,
                                                 bf16* __restrict__ o) {
  int row = blockIdx.x;
  const float* xr = x + (size_t)row * DM;
  float ss = 0.f;
  for (int i = threadIdx.x; i < DM; i += 256) { float v = xr[i]; ss += v * v; }
  for (int off = 32; off > 0; off >>= 1) ss += __shfl_down(ss, off);
  __shared__ float sred[4];
  __shared__ float sscale;
  if ((threadIdx.x & 63) == 0) sred[threadIdx.x >> 6] = ss;
  __syncthreads();
  if (threadIdx.x == 0) {
    float t = sred[0] + sred[1] + sred[2] + sred[3];
    sscale = rsqrtf(t / (float)DM + 1.1920929e-7f);
  }
  __syncthreads();
  float sc = sscale;
  bf16* orow = o + (size_t)row * DM;
  for (int i = threadIdx.x; i < DM; i += 256) orow[i] = from_f<bf16>(xr[i] * sc * w[i]);
}

// ======== 256x128 pipelined MFMA GEMM (8 waves, 4M x 2N) ========
// v2 of the 8-phase template: fragment PRE-READ pipeline — each phase's
// ds_reads feed the NEXT phase's MFMA, so the LDS drain overlaps the MFMA
// window instead of serializing before it.  Per-wave output 64x64 (acc = 64
// AGPR) frees the VGPRs for double-buffered fragments (5 sets x 16 VGPR).
// LDS 96 KiB: A = 2 bufs x 32 KB @ 0, B = 2 bufs x 16 KB @ 64 KB.
// Stage units of 16 KB (128 rows x 64 cols): A-lo/A-hi/B per K-tile.
// Phase schedule per tile t (buffers: A(t),B(t) in buf t&1):
//   q0: ds bq1<-B(t).n1 ; stage A-lo(t+1)->nxt ; bar ; MM(a0,bq0 -> m0n0) ; bar
//   q1: ds a1<-A(t).m1  ; stage A-hi(t+1)->nxt ; bar ; MM(a0,bq1 -> m0n1) ; bar
//   q2: stage B(t+2)->cur ; bar ; MM(a1,bq1 -> m1n1) ; vmcnt(2|0) ; bar
//   q3: ds a0<-A(t+1).m0, bq0'<-B(t+1).n0 ; bar ; MM(a1,bq0 -> m1n0) ; bar
// vmcnt(2) at q2 certifies A(t+1) both halves + B(t+1) (leaves B(t+2) in
// flight) before q3's cross-tile pre-reads.  nt must be even (uses: 16, 32).
template <int MODE>
__global__ __launch_bounds__(512, 1) void gemm256(const bf16* __restrict__ A,
                                                  const bf16* __restrict__ W,
                                                  int M, int N, int K,
                                                  bf16* __restrict__ Cx,
                                                  bf16* __restrict__ Cz, int nsplit,
                                                  float* __restrict__ Cf,
                                                  const float* __restrict__ R) {
  __shared__ ushort SH[49152];   // 96 KiB
  const int tid = threadIdx.x;
  const int lane = tid & 63, wv = tid >> 6;
  const int wr = wv >> 1, wc = wv & 1;          // 4M x 2N wave grid
  const int row15 = lane & 15, quad = lane >> 4;

  // XCD-aware block swizzle (grids are multiples of 8)
  int ntm = M >> 8, ntn = N >> 7, nwg = ntm * ntn;
  int bid = blockIdx.x;
  int swz = (bid & 7) * (nwg >> 3) + (bid >> 3);
  int bm0 = (swz % ntm) << 8, bn0 = (swz / ntm) << 7;

  const int nt = K >> 6;   // K-tiles (even)
  const ushort* Au = (const ushort*)A;
  const ushort* Wu = (const ushort*)W;
  const ushort* Ag = Au + (u32)bm0 * (u32)K;
  const ushort* Bg = Wu + (u32)bn0 * (u32)K;

  // staging coords: lane's inverse-swizzled chunk (st_16x32 involution)
  const int w4u = lane ^ (((lane >> 5) & 1) << 1);
  const int sub0 = wv, sub1 = wv + 8;
  const int r0 = ((sub0 >> 1) << 4) | (w4u >> 2);
  const int c0 = ((sub0 & 1) << 5) | ((w4u & 3) << 3);
  const int r1 = ((sub1 >> 1) << 4) | (w4u >> 2);
  const int c1 = ((sub1 & 1) << 5) | ((w4u & 3) << 3);
  ushort* shA = (ushort*)SH;            // 2 bufs x 16384 ushorts
  ushort* shB = (ushort*)SH + 32768;    // 2 bufs x 8192 ushorts

  auto stage = [&](const ushort* gbase, int rowoff, int tt, ushort* lbase) {
    gload16(gbase + (u32)(rowoff + r0) * (u32)K + (u32)(tt * 64 + c0), lbase + (sub0 << 9));
    gload16(gbase + (u32)(rowoff + r1) * (u32)K + (u32)(tt * 64 + c1), lbase + (sub1 << 9));
  };

  // fragment-read swizzled byte offset within a 1024B subtile
  const int Wsw = (((row15 << 6) | (quad << 4)) ^ (((row15 >> 3) & 1) << 5));
  const char* SHb = (const char*)SH;
  // ds_read byte bases per buffer (wave-local panel origin + swizzle)
  const int AB0 = (wr << 13) + Wsw;
  const int AB1 = 32768 + AB0;
  const int BB0 = 65536 + (wc << 13) + Wsw;
  const int BB1 = BB0 + 16384;

  short8 a0[2][2], a1[2][2], bq0A[2][2], bq0B[2][2], bq1[2][2];
  floatx4 acc[4][4] = {};

#define LDA_(dst, base, mh) do { _Pragma("unroll") for (int i_ = 0; i_ < 2; ++i_) \
  { _Pragma("unroll") for (int kk = 0; kk < 2; ++kk) \
    dst[i_][kk] = *(const short8*)(SHb + (base) + ((((mh)*2 + i_)*2 + kk) << 10)); } } while (0)
#define LDB_(dst, base, nh) do { _Pragma("unroll") for (int j_ = 0; j_ < 2; ++j_) \
  { _Pragma("unroll") for (int kk = 0; kk < 2; ++kk) \
    dst[j_][kk] = *(const short8*)(SHb + (base) + ((((nh)*2 + j_)*2 + kk) << 10)); } } while (0)
#define MM_(aset, bset, mh, nh) do { __builtin_amdgcn_s_setprio(1); \
  _Pragma("unroll") for (int i_ = 0; i_ < 2; ++i_) \
  { _Pragma("unroll") for (int j_ = 0; j_ < 2; ++j_) \
    { _Pragma("unroll") for (int kk = 0; kk < 2; ++kk) \
      acc[(mh)*2+i_][(nh)*2+j_] = __builtin_amdgcn_mfma_f32_16x16x32_bf16( \
          aset[i_][kk], bset[j_][kk], acc[(mh)*2+i_][(nh)*2+j_], 0, 0, 0); } } \
  __builtin_amdgcn_s_setprio(0); } while (0)

#define TILE_(t, ABc, BBc, ABn, BBn, BQU, BQF, CURB, NXTB) do { \
  int tp1 = (t) + 1, tp2 = (t) + 2; \
  /* q0 */ \
  LDB_(bq1, BBc, 1); \
  if (tp1 < nt) stage(Ag, 0, tp1, shA + (NXTB) * 16384); \
  barx(); MM_(a0, BQU, 0, 0); barx(); \
  /* q1 */ \
  LDA_(a1, ABc, 1); \
  if (tp1 < nt) stage(Ag, 128, tp1, shA + (NXTB) * 16384 + 8192); \
  barx(); MM_(a0, bq1, 0, 1); barx(); \
  /* q2 */ \
  if (tp2 < nt) stage(Bg, 0, tp2, shB + (CURB) * 8192); \
  barx(); MM_(a1, bq1, 1, 1); \
  if (tp2 < nt) vmw2(); else vmw0(); \
  barx(); \
  /* q3 */ \
  if (tp1 < nt) { LDA_(a0, ABn, 0); LDB_(BQF, BBn, 0); } \
  barx(); MM_(a1, BQU, 1, 0); barx(); \
} while (0)

  // prologue: B(0), A(0)-lo, A(0)-hi -> buf0 ; B(1) -> buf1
  stage(Bg, 0, 0, shB);
  stage(Ag, 0, 0, shA);
  stage(Ag, 128, 0, shA + 8192);
  if (nt > 1) { stage(Bg, 0, 1, shB + 8192); vmw2(); } else { vmw0(); }
  barx();
  LDA_(a0, AB0, 0);
  LDB_(bq0A, BB0, 0);

  for (int t = 0; t < nt; t += 2) {
    TILE_(t,     AB0, BB0, AB1, BB1, bq0A, bq0B, 0, 1);
    TILE_(t + 1, AB1, BB1, AB0, BB0, bq0B, bq0A, 1, 0);
  }
#undef TILE_
#undef MM_
#undef LDB_
#undef LDA_

  // epilogue
#pragma unroll
  for (int mi = 0; mi < 4; ++mi) {
#pragma unroll
    for (int ni = 0; ni < 4; ++ni) {
#pragma unroll
      for (int reg = 0; reg < 4; ++reg) {
        int grow = bm0 + wr * 64 + mi * 16 + quad * 4 + reg;
        int gcol = bn0 + wc * 64 + ni * 16 + row15;
        float v = acc[mi][ni][reg];
        if (MODE == 1) {
          if (gcol < nsplit) {
            Cx[(u32)grow * DI + (u32)gcol] = from_f<bf16>(v);
          } else {
            Cz[(u32)grow * DI + (u32)(gcol - nsplit)] = from_f<bf16>(fsilu(v));
          }
        } else {
          u32 o = (u32)grow * (u32)N + (u32)gcol;
          Cf[o] = v + R[o];
        }
      }
    }
  }
}

// ======== 128x128 MFMA GEMM (kept for dt_proj, K=64) ========
#define TM 128
#define TN 128
#define TK 32
#define LDK 40
template <int MODE>
__global__ __launch_bounds__(256) void gemm_mfma(const bf16* __restrict__ A,
                                                 const bf16* __restrict__ W,
                                                 int M, int N, int K,
                                                 bf16* __restrict__ Cx,
                                                 bf16* __restrict__ Cz, int nsplit,
                                                 float* __restrict__ Cf,
                                                 const float* __restrict__ R,
                                                 const float* __restrict__ bias) {
  __shared__ ushort Asm[TM][TK];   // linear — required by global_load_lds
  __shared__ ushort Bsm[TN][TK];
  int bm = blockIdx.y * TM, bn = blockIdx.x * TN;
  int tid = threadIdx.x;
  int lane = tid & 63, wave = tid >> 6;
  int wm = (wave & 1) * 64, wn = (wave >> 1) * 64;
  int row15 = lane & 15, quad = lane >> 4;

  int srow = lane >> 2;          // 0..15
  int scol = (lane & 3) * 8;     // 0,8,16,24
  int s0 = wave * 2, s1 = wave * 2 + 1;

  const ushort* Au = (const ushort*)A;
  const ushort* Wu = (const ushort*)W;
  const ushort* ag0 = Au + (size_t)(bm + s0 * 16 + srow) * K + scol;
  const ushort* ag1 = Au + (size_t)(bm + s1 * 16 + srow) * K + scol;
  const ushort* bg0 = Wu + (size_t)(bn + s0 * 16 + srow) * K + scol;
  const ushort* bg1 = Wu + (size_t)(bn + s1 * 16 + srow) * K + scol;
  ushort* la0 = &Asm[s0 * 16][0];
  ushort* la1 = &Asm[s1 * 16][0];
  ushort* lb0 = &Bsm[s0 * 16][0];
  ushort* lb1 = &Bsm[s1 * 16][0];

  floatx4 acc[4][4] = {};

  for (int k0 = 0; k0 < K; k0 += TK) {
    gload16(ag0 + k0, la0);
    gload16(ag1 + k0, la1);
    gload16(bg0 + k0, lb0);
    gload16(bg1 + k0, lb1);
    __syncthreads();
    short8 a_f[4], b_f[4];
#pragma unroll
    for (int i = 0; i < 4; ++i)
      a_f[i] = *(const short8*)&Asm[wm + i * 16 + row15][quad * 8];
#pragma unroll
    for (int j = 0; j < 4; ++j)
      b_f[j] = *(const short8*)&Bsm[wn + j * 16 + row15][quad * 8];
#pragma unroll
    for (int i = 0; i < 4; ++i)
#pragma unroll
      for (int j = 0; j < 4; ++j)
        acc[i][j] = __builtin_amdgcn_mfma_f32_16x16x32_bf16(a_f[i], b_f[j], acc[i][j], 0, 0, 0);
    __syncthreads();
  }
#pragma unroll
  for (int mi = 0; mi < 4; ++mi) {
#pragma unroll
    for (int ni = 0; ni < 4; ++ni) {
#pragma unroll
      for (int reg = 0; reg < 4; ++reg) {
        int grow = bm + wm + mi * 16 + quad * 4 + reg;
        int gcol = bn + wn + ni * 16 + row15;
        float v = acc[mi][ni][reg];
        if (MODE == 1) {
          if (gcol < nsplit) {
            Cx[(size_t)grow * DI + gcol] = from_f<bf16>(v);
          } else {
            Cz[(size_t)grow * DI + (gcol - nsplit)] = from_f<bf16>(fsilu(v));
          }
        } else if (MODE == 2) {
          size_t o = (size_t)grow * N + gcol;
          Cf[o] = v + R[o];
        } else {  // MODE 3: dt softplus
          float t = v + bias[gcol];
          float sp = (t > 20.f) ? t : __logf(1.f + __expf(t));
          Cx[(size_t)grow * N + gcol] = from_f<bf16>(sp);
        }
      }
    }
  }
}

// ======== x_proj split-K MFMA: xdbl[BL,96] += u[BL,2048-slice] @ xpw^T ========
#define XKS 128
__global__ __launch_bounds__(256) void xproj_k(const bf16* __restrict__ u,
                                               const bf16* __restrict__ w,
                                               float* __restrict__ xdbl) {
  __shared__ ushort Asm[128][LDK];
  __shared__ ushort Bsm[96][LDK];
  int kbase = blockIdx.x * XKS;
  int bm = blockIdx.y * 128;
  int tid = threadIdx.x;
  int lane = tid & 63, wave = tid >> 6;
  int row15 = lane & 15, quad = lane >> 4;
  int srow = tid >> 1, skoff = (tid & 1) * 16;

  floatx4 acc[2][6] = {};
  const ushort* Au = (const ushort*)u;
  const ushort* Wu = (const ushort*)w;
  for (int k0 = kbase; k0 < kbase + XKS; k0 += TK) {
    const ushort* ag = Au + (size_t)(bm + srow) * DI + k0 + skoff;
    *(short8*)&Asm[srow][skoff]     = *(const short8*)ag;
    *(short8*)&Asm[srow][skoff + 8] = *(const short8*)(ag + 8);
    if (tid < 192) {
      const ushort* wg = Wu + (size_t)srow * DI + k0 + skoff;
      *(short8*)&Bsm[srow][skoff]     = *(const short8*)wg;
      *(short8*)&Bsm[srow][skoff + 8] = *(const short8*)(wg + 8);
    }
    __syncthreads();
    short8 a_f[2], b_f[6];
#pragma unroll
    for (int i = 0; i < 2; ++i)
      a_f[i] = *(const short8*)&Asm[wave * 32 + i * 16 + row15][quad * 8];
#pragma unroll
    for (int j = 0; j < 6; ++j)
      b_f[j] = *(const short8*)&Bsm[j * 16 + row15][quad * 8];
#pragma unroll
    for (int i = 0; i < 2; ++i)
#pragma unroll
      for (int j = 0; j < 6; ++j)
        acc[i][j] = __builtin_amdgcn_mfma_f32_16x16x32_bf16(a_f[i], b_f[j], acc[i][j], 0, 0, 0);
    __syncthreads();
  }
#pragma unroll
  for (int mi = 0; mi < 2; ++mi)
#pragma unroll
    for (int nj = 0; nj < 6; ++nj)
#pragma unroll
      for (int reg = 0; reg < 4; ++reg) {
        int grow = bm + wave * 32 + mi * 16 + quad * 4 + reg;
        int gcol = nj * 16 + row15;
        atomicAdd(&xdbl[(size_t)grow * DXP + gcol], acc[mi][nj][reg]);
      }
}

// ---- extract xdbl[:, 0:64] -> bf16 [BL, 64] for the dt MFMA ----
__global__ __launch_bounds__(256) void dtex_k(const float* __restrict__ xdbl,
                                              bf16* __restrict__ dtin) {
  int i = blockIdx.x * 256 + threadIdx.x;  // BL*DR
  int r = i >> 6, c = i & 63;
  dtin[i] = from_f<bf16>(xdbl[(size_t)r * DXP + c]);
}

// ---------------- causal depthwise conv (K=4) + SiLU ----------------
#define TSTRIP 8
__global__ __launch_bounds__(256) void conv_silu_k(const bf16* __restrict__ xin,
                                                   const float* __restrict__ cw,
                                                   const float* __restrict__ cb,
                                                   bf16* __restrict__ u) {
  int blk = blockIdx.x;                   // NB * (SL/TSTRIP) blocks
  int b = blk >> 8;
  int l0 = (blk & 255) * TSTRIP;
  int c0 = threadIdx.x * 8;

  float4 cw4[8];
  const float4* cwp = (const float4*)cw;
#pragma unroll
  for (int j = 0; j < 8; ++j) cw4[j] = cwp[c0 + j];
  float cbv[8];
  {
    float4 cb0 = *(const float4*)&cb[c0];
    float4 cb1 = *(const float4*)&cb[c0 + 4];
    cbv[0] = cb0.x; cbv[1] = cb0.y; cbv[2] = cb0.z; cbv[3] = cb0.w;
    cbv[4] = cb1.x; cbv[5] = cb1.y; cbv[6] = cb1.z; cbv[7] = cb1.w;
  }

  const ushort* base = (const ushort*)xin + ((size_t)(b * SL + l0) * DI + c0);
  ushort* ubase = (ushort*)u + ((size_t)(b * SL + l0) * DI + c0);

  short8 zz = {};
  short8 w0 = zz, w1 = zz, w2 = zz;
  if (l0 >= 3) {
    w0 = *(const short8*)(base - 3 * DI);
    w1 = *(const short8*)(base - 2 * DI);
    w2 = *(const short8*)(base - 1 * DI);
  }
#pragma unroll
  for (int l = 0; l < TSTRIP; ++l) {
    short8 w3 = *(const short8*)(base + (ptrdiff_t)l * DI);
    short8 outv;
#pragma unroll
    for (int j = 0; j < 8; ++j) {
      float a = cbv[j]
              + bfbits2f((unsigned short)w0[j]) * cw4[j].x
              + bfbits2f((unsigned short)w1[j]) * cw4[j].y
              + bfbits2f((unsigned short)w2[j]) * cw4[j].z
              + bfbits2f((unsigned short)w3[j]) * cw4[j].w;
      outv[j] = f2bfbits(fsilu(a));
    }
    *(short8*)(ubase + (ptrdiff_t)l * DI) = outv;
    w0 = w1; w1 = w2; w2 = w3;
  }
}

// ======== chunked selective scan ========
__global__ __launch_bounds__(256) void scan_p1(const bf16* __restrict__ dts,
                                               const bf16* __restrict__ u,
                                               const float* __restrict__ xdbl,
                                               const float* __restrict__ A_log,
                                               float* __restrict__ Pbuf,
                                               float* __restrict__ Qbuf) {
  int bid = blockIdx.x;
  int b = bid >> 8;
  int c = (bid >> 3) & (NC - 1);
  int d = (bid & 7) * 256 + threadIdx.x;

  float A[DS], h[DS], P[DS];
#pragma unroll
  for (int s = 0; s < DS; ++s) {
    A[s] = -__expf(A_log[d * DS + s]);
    h[s] = 0.f; P[s] = 1.f;
  }
  size_t bl0 = (size_t)b * SL + c * CL;
  size_t base = bl0 * DI + d;
  size_t xb = bl0 * DXP + DR;
  for (int l = 0; l < CL; ++l) {
    float dtv = to_f(dts[base]);
    float uv = to_f(u[base]);
    float du = dtv * uv;
#pragma unroll
    for (int s = 0; s < DS; ++s) {
      float Bv = xdbl[xb + s];
      float dA = __expf(dtv * A[s]);
      h[s] = dA * h[s] + du * Bv;
      P[s] *= dA;
    }
    base += DI;
    xb += DXP;
  }
  size_t o = ((size_t)(b * NC + c) * DS) * DI + d;
#pragma unroll
  for (int s = 0; s < DS; ++s) {
    Pbuf[o + (size_t)s * DI] = P[s];
    Qbuf[o + (size_t)s * DI] = h[s];
  }
}

__global__ __launch_bounds__(256) void scan_p2(float* __restrict__ Pbuf,
                                               float* __restrict__ Qbuf) {
  int bid = blockIdx.x;
  int b = bid >> 7;
  int s = (bid >> 3) & (DS - 1);
  int d = (bid & 7) * 256 + threadIdx.x;
  float h = 0.f;
  for (int c = 0; c < NC; ++c) {
    size_t idx = ((size_t)((b * NC + c) * DS + s)) * DI + d;
    float Pv = Pbuf[idx];
    float qv = Qbuf[idx];
    Qbuf[idx] = h;
    h = Pv * h + qv;
  }
}

__global__ __launch_bounds__(256) void scan_p3(const bf16* __restrict__ dts,
                                               bf16* __restrict__ u,
                                               const float* __restrict__ xdbl,
                                               const float* __restrict__ A_log,
                                               const float* __restrict__ Dp,
                                               const bf16* __restrict__ g,
                                               const float* __restrict__ Qbuf) {
  int bid = blockIdx.x;
  int b = bid >> 8;
  int c = (bid >> 3) & (NC - 1);
  int d = (bid & 7) * 256 + threadIdx.x;

  float A[DS], h[DS];
  size_t o = ((size_t)(b * NC + c) * DS) * DI + d;
#pragma unroll
  for (int s = 0; s < DS; ++s) {
    A[s] = -__expf(A_log[d * DS + s]);
    h[s] = Qbuf[o + (size_t)s * DI];
  }
  float Dd = Dp[d];
  size_t bl0 = (size_t)b * SL + c * CL;
  size_t base = bl0 * DI + d;
  size_t xb = bl0 * DXP + DR;
  for (int l = 0; l < CL; ++l) {
    float dtv = to_f(dts[base]);
    float uv = to_f(u[base]);
    float gv = to_f(g[base]);
    float du = dtv * uv;
    float p0 = 0.f, p1 = 0.f, p2 = 0.f, p3 = 0.f;
#pragma unroll
    for (int s = 0; s < DS; s += 4) {
      float dA0 = __expf(dtv * A[s + 0]);
      float dA1 = __expf(dtv * A[s + 1]);
      float dA2 = __expf(dtv * A[s + 2]);
      float dA3 = __expf(dtv * A[s + 3]);
      h[s + 0] = dA0 * h[s + 0] + du * xdbl[xb + s + 0];
      h[s + 1] = dA1 * h[s + 1] + du * xdbl[xb + s + 1];
      h[s + 2] = dA2 * h[s + 2] + du * xdbl[xb + s + 2];
      h[s + 3] = dA3 * h[s + 3] + du * xdbl[xb + s + 3];
      p0 += h[s + 0] * xdbl[xb + DS + s + 0];
      p1 += h[s + 1] * xdbl[xb + DS + s + 1];
      p2 += h[s + 2] * xdbl[xb + DS + s + 2];
      p3 += h[s + 3] * xdbl[xb + DS + s + 3];
    }
    float yv = ((p0 + p1) + (p2 + p3)) + Dd * uv;
    u[base] = from_f<bf16>(yv * gv);
    base += DI;
    xb += DXP;
  }
}

extern "C" void kernel_launch(void* const* d_in, const int* in_sizes, int n_in,
                              void* d_out, int out_size, void* d_ws, size_t ws_size,
                              hipStream_t stream) {
  const float* x        = (const float*)d_in[0];
  const float* norm_w   = (const float*)d_in[1];
  const float* in_projw = (const float*)d_in[2];
  const float* conv_w   = (const float*)d_in[3];
  const float* conv_b   = (const float*)d_in[4];
  const float* x_projw  = (const float*)d_in[5];
  const float* dt_projw = (const float*)d_in[6];
  const float* dt_projb = (const float*)d_in[7];
  const float* A_log    = (const float*)d_in[8];
  const float* Dp       = (const float*)d_in[9];
  const float* out_projw= (const float*)d_in[10];
  float* out = (float*)d_out;

  // ---- workspace (~104 MiB), lifetime overlays ----
  char* wsb = (char*)d_ws;
  bf16* x_buf  = (bf16*)wsb;                           // x half; later dt; later opw_bf
  bf16* z_buf  = (bf16*)(wsb + (size_t)BL * DI * 2);   // silu(z) gate
  bf16* u_buf  = (bf16*)(wsb + (size_t)BL * DI * 4);   // xnorm_bf (early) then u/y
  char* ovl    = wsb + (size_t)BL * DI * 6;            // 8 MiB overlay
  bf16* ipw_bf = (bf16*)ovl;                           // phase A: in_proj w bf16 (8 MiB)
  // phase B overlay (after in_proj):
  float* xdbl   = (float*)ovl;                                 // 3 MiB
  bf16*  xpw_bf = (bf16*)(ovl + 3145728);                      // 0.375 MiB
  bf16*  dtw_bf = (bf16*)(ovl + 3538944);                      // 0.25 MiB
  bf16*  dtin_bf= (bf16*)(ovl + 3801088);                      // 1 MiB
  bf16* xnorm_bf = u_buf;
  bf16* dt_buf   = x_buf;   // x half dead after conv
  bf16* opw_bf   = x_buf;   // dt dead after scan p3
  float* Pbuf = out;        // d_out scratch until out_proj
  float* Qbuf = out + (size_t)NB * NC * DS * DI;

  // 1. in_proj weights -> bf16
  f2b_k<<<(2 * DI * DM) / 256, 256, 0, stream>>>(in_projw, ipw_bf, 2 * DI * DM);
  // 2. RMSNorm -> bf16
  rmsnorm_k<<<BL, 256, 0, stream>>>(x, norm_w, xnorm_bf);
  // 3. in_proj (256x128 pipelined MFMA): x half -> x_buf ; z half silu -> z_buf
  gemm256<1><<<(BL / 256) * (2 * DI / 128), 512, 0, stream>>>(
      xnorm_bf, ipw_bf, BL, 2 * DI, DM, x_buf, z_buf, DI, nullptr, nullptr);
  // 4. causal conv + silu -> u_buf (time-strip, register sliding window)
  conv_silu_k<<<NB * (SL / TSTRIP), 256, 0, stream>>>(x_buf, conv_w, conv_b, u_buf);
  // 5. x_proj: zero xdbl, convert weights, split-K MFMA with atomic accumulate
  hipMemsetAsync(xdbl, 0, (size_t)BL * DXP * sizeof(float), stream);
  f2b_k<<<(DXP * DI + 255) / 256, 256, 0, stream>>>(x_projw, xpw_bf, DXP * DI);
  f2b_k<<<(DI * DR) / 256, 256, 0, stream>>>(dt_projw, dtw_bf, DI * DR);
  xproj_k<<<dim3(DI / XKS, BL / 128), 256, 0, stream>>>(u_buf, xpw_bf, xdbl);
  // 6. dt input slice -> bf16, dt_proj (MFMA, fused bias+softplus) -> dt_buf
  dtex_k<<<(BL * DR) / 256, 256, 0, stream>>>(xdbl, dtin_bf);
  gemm_mfma<3><<<dim3(DI / TN, BL / TM), 256, 0, stream>>>(
      dtin_bf, dtw_bf, BL, DI, DR, dt_buf, nullptr, 0, nullptr, nullptr, dt_projb);
  // 7. chunked scan
  scan_p1<<<NB * NC * (DI / 256), 256, 0, stream>>>(dt_buf, u_buf, xdbl, A_log, Pbuf, Qbuf);
  scan_p2<<<NB * DS * (DI / 256), 256, 0, stream>>>(Pbuf, Qbuf);
  scan_p3<<<NB * NC * (DI / 256), 256, 0, stream>>>(dt_buf, u_buf, xdbl, A_log, Dp, z_buf, Qbuf);
  // 8. out_proj weights -> bf16, out_proj (256x128 pipelined) + fused residual -> d_out
  f2b_k<<<(DM * DI) / 256, 256, 0, stream>>>(out_projw, opw_bf, DM * DI);
  gemm256<2><<<(BL / 256) * (DM / 128), 512, 0, stream>>>(
      u_buf, opw_bf, BL, DM, DI, nullptr, nullptr, 0, out, x);
}

// Round 5
// 466.028 us; speedup vs baseline: 1.0800x; 1.0800x over previous
//
#include <hip/hip_runtime.h>
#include <hip/hip_bf16.h>
#include <math.h>

#define DM 1024   // d_model
#define DI 2048   // d_inner
#define DS 16     // d_state
#define DC 4      // d_conv
#define DR 64     // dt_rank
#define NB 4      // batch
#define SL 2048   // seqlen
#define BL (NB * SL)        // 8192 rows
#define DXP (DR + 2 * DS)   // 96
#define NC 32               // scan chunks
#define CL (SL / NC)        // 64 steps per chunk

typedef __hip_bfloat16 bf16;
typedef __attribute__((ext_vector_type(8))) short short8;
typedef __attribute__((ext_vector_type(4))) float floatx4;
typedef unsigned int u32;

__device__ __forceinline__ float to_f(float v) { return v; }
__device__ __forceinline__ float to_f(bf16 v) { return __bfloat162float(v); }
template <typename T> __device__ __forceinline__ T from_f(float v);
template <> __device__ __forceinline__ float from_f<float>(float v) { return v; }
template <> __device__ __forceinline__ bf16 from_f<bf16>(float v) { return __float2bfloat16(v); }

__device__ __forceinline__ float bfbits2f(unsigned short u) {
  u32 b = ((u32)u) << 16;
  return __builtin_bit_cast(float, b);
}
__device__ __forceinline__ short f2bfbits(float v) {
  bf16 b = __float2bfloat16(v);
  return __builtin_bit_cast(short, b);
}
// fast silu: x * rcp(1+e^-x)  (v_rcp_f32, ~1 ulp — fine for bf16 outputs)
__device__ __forceinline__ float fsilu(float v) {
  return v * __builtin_amdgcn_rcpf(1.f + __expf(-v));
}

// async global->LDS, 16B per lane. LDS dest = wave-uniform base + lane*16.
__device__ __forceinline__ void gload16(const ushort* g, ushort* l) {
  __builtin_amdgcn_global_load_lds((const __attribute__((address_space(1))) void*)g,
                                   (__attribute__((address_space(3))) void*)l,
                                   16, 0, 0);
}

__device__ __forceinline__ void vmw4() { asm volatile("s_waitcnt vmcnt(4)" ::: "memory"); }
__device__ __forceinline__ void vmw2() { asm volatile("s_waitcnt vmcnt(2)" ::: "memory"); }
__device__ __forceinline__ void vmw0() { asm volatile("s_waitcnt vmcnt(0)" ::: "memory"); }
// raw barrier (NO implicit vmcnt drain) with compiler-only memory fences so
// LDS reads/stages can't migrate across phases.
__device__ __forceinline__ void barx() {
  asm volatile("" ::: "memory");
  __builtin_amdgcn_s_barrier();
  asm volatile("" ::: "memory");
}

// ---------------- fp32 -> bf16 conversion ----------------
__global__ __launch_bounds__(256) void f2b_k(const float* __restrict__ src,
                                             bf16* __restrict__ dst, int n) {
  int i = blockIdx.x * 256 + threadIdx.x;
  if (i < n) dst[i] = from_f<bf16>(src[i]);
}

// ---------------- RMSNorm (bf16 out) ----------------
__global__ __launch_bounds__(256) void rmsnorm_k(const float* __restrict__ x,
                                                 const float* __restrict__ w,
                                                 bf16* __restrict__ o) {
  int row = blockIdx.x;
  const float* xr = x + (size_t)row * DM;
  float ss = 0.f;
  for (int i = threadIdx.x; i < DM; i += 256) { float v = xr[i]; ss += v * v; }
  for (int off = 32; off > 0; off >>= 1) ss += __shfl_down(ss, off);
  __shared__ float sred[4];
  __shared__ float sscale;
  if ((threadIdx.x & 63) == 0) sred[threadIdx.x >> 6] = ss;
  __syncthreads();
  if (threadIdx.x == 0) {
    float t = sred[0] + sred[1] + sred[2] + sred[3];
    sscale = rsqrtf(t / (float)DM + 1.1920929e-7f);
  }
  __syncthreads();
  float sc = sscale;
  bf16* orow = o + (size_t)row * DM;
  for (int i = threadIdx.x; i < DM; i += 256) orow[i] = from_f<bf16>(xr[i] * sc * w[i]);
}

// ======== 256x256 8-phase pipelined MFMA GEMM (in_proj; R3-verified 85.7us) ========
// st_16x32 LDS swizzle (T2) via pre-swizzled global source + swizzled ds_read,
// half-tile prefetch with counted vmcnt (T3+T4), setprio around MFMA (T5).
// Geometry: BM=BN=256, BK=64, 8 waves (2Mx4N), per-wave output 128x64,
// LDS = 128 KiB.  Grid must be a multiple of 8, K/64 even.
template <int MODE>
__global__ __launch_bounds__(512, 1) void gemm256(const bf16* __restrict__ A,
                                                  const bf16* __restrict__ W,
                                                  int M, int N, int K,
                                                  bf16* __restrict__ Cx,
                                                  bf16* __restrict__ Cz, int nsplit,
                                                  float* __restrict__ Cf,
                                                  const float* __restrict__ R) {
  __shared__ ushort SH[65536];   // 128 KiB: A @ 0..64K, B @ 64K..128K (bytes)
  const int tid = threadIdx.x;
  const int lane = tid & 63, wv = tid >> 6;
  const int wr = wv >> 2, wc = wv & 3;
  const int row15 = lane & 15, quad = lane >> 4;

  // XCD-aware block swizzle (grids used here are multiples of 8)
  int ntm = M >> 8, ntn = N >> 8, nwg = ntm * ntn;
  int bid = blockIdx.x;
  int swz = (bid & 7) * (nwg >> 3) + (bid >> 3);
  int bm0 = (swz % ntm) << 8, bn0 = (swz / ntm) << 8;

  const int nt = K >> 6;   // K-tiles
  const ushort* Au = (const ushort*)A;
  const ushort* Wu = (const ushort*)W;

  // staging: lane's inverse-swizzled source chunk (involution in chunk space)
  const int w4u = lane ^ (((lane >> 5) & 1) << 1);
  // fragment-read swizzled byte offset within a 1024B subtile
  const int Wsw = (((row15 << 6) | (quad << 4)) ^ (((row15 >> 3) & 1) << 5));
  const char* SHb = (const char*)SH;
  // ds_read base byte offsets (cur encoded in the two variants)
  const int Abase0 = (wr << 14) + Wsw;
  const int Abase1 = 32768 + (wr << 14) + Wsw;
  const int Bbase0 = 65536 + ((wc >> 1) << 14) + ((wc & 1) << 13) + Wsw;
  const int Bbase1 = Bbase0 + 32768;

  auto stageA = [&](int tt, int half, int buf) {
    const ushort* g = Au + (size_t)(bm0 + half * 128) * K + tt * 64;
    char* lds = (char*)SH + (size_t)(buf * 2 + half) * 16384;
#pragma unroll
    for (int i = 0; i < 2; ++i) {
      int sub = wv + i * 8;
      int r = ((sub >> 1) << 4) | (w4u >> 2);
      int ce = ((sub & 1) << 5) | ((w4u & 3) << 3);
      gload16(g + (size_t)r * K + ce, (ushort*)(lds + sub * 1024));
    }
  };
  auto stageB = [&](int tt, int half, int buf) {
    const ushort* g = Wu + (size_t)(bn0 + half * 128) * K + tt * 64;
    char* lds = (char*)SH + 65536 + (size_t)(buf * 2 + half) * 16384;
#pragma unroll
    for (int i = 0; i < 2; ++i) {
      int sub = wv + i * 8;
      int r = ((sub >> 1) << 4) | (w4u >> 2);
      int ce = ((sub & 1) << 5) | ((w4u & 3) << 3);
      gload16(g + (size_t)r * K + ce, (ushort*)(lds + sub * 1024));
    }
  };

  short8 a_f[4][2], bq[2][2][2];   // bq[nh][ni][kk]; bq[0] retained q0->q3
  floatx4 acc[8][4] = {};

#define LDA_(base, mh) do { _Pragma("unroll") for (int mi = 0; mi < 4; ++mi) \
  { _Pragma("unroll") for (int kk = 0; kk < 2; ++kk) \
    a_f[mi][kk] = *(const short8*)(SHb + (base) + ((((mh)*4 + mi)*2 + kk) << 10)); } } while (0)
#define LDB_(base, nh) do { _Pragma("unroll") for (int ni = 0; ni < 2; ++ni) \
  { _Pragma("unroll") for (int kk = 0; kk < 2; ++kk) \
    bq[nh][ni][kk] = *(const short8*)(SHb + (base) + (((((nh)*2 + ni)*2 + kk)) << 10)); } } while (0)
#define MM_(mh, nh) do { __builtin_amdgcn_s_setprio(1); \
  _Pragma("unroll") for (int mi = 0; mi < 4; ++mi) \
  { _Pragma("unroll") for (int ni = 0; ni < 2; ++ni) \
    { _Pragma("unroll") for (int kk = 0; kk < 2; ++kk) \
      acc[(mh)*4+mi][(nh)*2+ni] = __builtin_amdgcn_mfma_f32_16x16x32_bf16( \
          a_f[mi][kk], bq[nh][ni][kk], acc[(mh)*4+mi][(nh)*2+ni], 0, 0, 0); } } \
  __builtin_amdgcn_s_setprio(0); } while (0)

#define TILE_(t, AB, BB, curbuf, nxtbuf) do { \
  int tp1 = (t) + 1, tp2 = (t) + 2; \
  LDA_(AB, 0); LDB_(BB, 0); \
  if (tp1 < nt) stageA(tp1, 0, nxtbuf); \
  barx(); MM_(0, 0); barx(); \
  LDB_(BB, 1); \
  if (tp1 < nt) stageA(tp1, 1, nxtbuf); \
  barx(); MM_(0, 1); barx(); \
  LDA_(AB, 1); \
  if (tp2 < nt) stageB(tp2, 0, curbuf); \
  barx(); MM_(1, 1); barx(); \
  if (tp2 < nt) stageB(tp2, 1, curbuf); \
  barx(); MM_(1, 0); \
  if (tp2 < nt) vmw4(); else vmw0(); \
  barx(); \
} while (0)

  // prologue: tile0's 4 halves + tile1's B halves (6 halves = 12 loads)
  stageB(0, 0, 0); stageB(0, 1, 0); stageA(0, 0, 0); stageA(0, 1, 0);
  stageB(1, 0, 1); stageB(1, 1, 1);
  vmw4();   // tile0 complete; tile1's B halves (4 loads) in flight
  barx();

  for (int t = 0; t < nt; t += 2) {
    TILE_(t, Abase0, Bbase0, 0, 1);
    TILE_(t + 1, Abase1, Bbase1, 1, 0);
  }
#undef TILE_
#undef MM_
#undef LDB_
#undef LDA_

  // epilogue
#pragma unroll
  for (int mi8 = 0; mi8 < 8; ++mi8) {
#pragma unroll
    for (int ni4 = 0; ni4 < 4; ++ni4) {
#pragma unroll
      for (int reg = 0; reg < 4; ++reg) {
        int grow = bm0 + wr * 128 + mi8 * 16 + quad * 4 + reg;
        int gcol = bn0 + wc * 64 + ni4 * 16 + row15;
        float v = acc[mi8][ni4][reg];
        if (MODE == 1) {
          if (gcol < nsplit) {
            Cx[(size_t)grow * DI + gcol] = from_f<bf16>(v);
          } else {
            Cz[(size_t)grow * DI + (gcol - nsplit)] = from_f<bf16>(fsilu(v));
          }
        } else {
          size_t o = (size_t)grow * N + gcol;
          Cf[o] = v + R[o];
        }
      }
    }
  }
}

// ======== 256x128 pipelined MFMA GEMM (out_proj; R4-verified, full grid at N=1024) ====
// 8 waves (4M x 2N), per-wave 64x64; fragment pre-read pipeline; LDS 96 KiB.
template <int MODE>
__global__ __launch_bounds__(512, 1) void gemm_np(const bf16* __restrict__ A,
                                                  const bf16* __restrict__ W,
                                                  int M, int N, int K,
                                                  bf16* __restrict__ Cx,
                                                  bf16* __restrict__ Cz, int nsplit,
                                                  float* __restrict__ Cf,
                                                  const float* __restrict__ R) {
  __shared__ ushort SH[49152];   // 96 KiB
  const int tid = threadIdx.x;
  const int lane = tid & 63, wv = tid >> 6;
  const int wr = wv >> 1, wc = wv & 1;          // 4M x 2N wave grid
  const int row15 = lane & 15, quad = lane >> 4;

  // XCD-aware block swizzle (grids are multiples of 8)
  int ntm = M >> 8, ntn = N >> 7, nwg = ntm * ntn;
  int bid = blockIdx.x;
  int swz = (bid & 7) * (nwg >> 3) + (bid >> 3);
  int bm0 = (swz % ntm) << 8, bn0 = (swz / ntm) << 7;

  const int nt = K >> 6;   // K-tiles (even)
  const ushort* Au = (const ushort*)A;
  const ushort* Wu = (const ushort*)W;
  const ushort* Ag = Au + (u32)bm0 * (u32)K;
  const ushort* Bg = Wu + (u32)bn0 * (u32)K;

  // staging coords: lane's inverse-swizzled chunk (st_16x32 involution)
  const int w4u = lane ^ (((lane >> 5) & 1) << 1);
  const int sub0 = wv, sub1 = wv + 8;
  const int r0 = ((sub0 >> 1) << 4) | (w4u >> 2);
  const int c0 = ((sub0 & 1) << 5) | ((w4u & 3) << 3);
  const int r1 = ((sub1 >> 1) << 4) | (w4u >> 2);
  const int c1 = ((sub1 & 1) << 5) | ((w4u & 3) << 3);
  ushort* shA = (ushort*)SH;            // 2 bufs x 16384 ushorts
  ushort* shB = (ushort*)SH + 32768;    // 2 bufs x 8192 ushorts

  auto stage = [&](const ushort* gbase, int rowoff, int tt, ushort* lbase) {
    gload16(gbase + (u32)(rowoff + r0) * (u32)K + (u32)(tt * 64 + c0), lbase + (sub0 << 9));
    gload16(gbase + (u32)(rowoff + r1) * (u32)K + (u32)(tt * 64 + c1), lbase + (sub1 << 9));
  };

  // fragment-read swizzled byte offset within a 1024B subtile
  const int Wsw = (((row15 << 6) | (quad << 4)) ^ (((row15 >> 3) & 1) << 5));
  const char* SHb = (const char*)SH;
  const int AB0 = (wr << 13) + Wsw;
  const int AB1 = 32768 + AB0;
  const int BB0 = 65536 + (wc << 13) + Wsw;
  const int BB1 = BB0 + 16384;

  short8 a0[2][2], a1[2][2], bq0A[2][2], bq0B[2][2], bq1[2][2];
  floatx4 acc[4][4] = {};

#define LDA_(dst, base, mh) do { _Pragma("unroll") for (int i_ = 0; i_ < 2; ++i_) \
  { _Pragma("unroll") for (int kk = 0; kk < 2; ++kk) \
    dst[i_][kk] = *(const short8*)(SHb + (base) + ((((mh)*2 + i_)*2 + kk) << 10)); } } while (0)
#define LDB_(dst, base, nh) do { _Pragma("unroll") for (int j_ = 0; j_ < 2; ++j_) \
  { _Pragma("unroll") for (int kk = 0; kk < 2; ++kk) \
    dst[j_][kk] = *(const short8*)(SHb + (base) + ((((nh)*2 + j_)*2 + kk) << 10)); } } while (0)
#define MM_(aset, bset, mh, nh) do { __builtin_amdgcn_s_setprio(1); \
  _Pragma("unroll") for (int i_ = 0; i_ < 2; ++i_) \
  { _Pragma("unroll") for (int j_ = 0; j_ < 2; ++j_) \
    { _Pragma("unroll") for (int kk = 0; kk < 2; ++kk) \
      acc[(mh)*2+i_][(nh)*2+j_] = __builtin_amdgcn_mfma_f32_16x16x32_bf16( \
          aset[i_][kk], bset[j_][kk], acc[(mh)*2+i_][(nh)*2+j_], 0, 0, 0); } } \
  __builtin_amdgcn_s_setprio(0); } while (0)

#define TILE_(t, ABc, BBc, ABn, BBn, BQU, BQF, CURB, NXTB) do { \
  int tp1 = (t) + 1, tp2 = (t) + 2; \
  /* q0 */ \
  LDB_(bq1, BBc, 1); \
  if (tp1 < nt) stage(Ag, 0, tp1, shA + (NXTB) * 16384); \
  barx(); MM_(a0, BQU, 0, 0); barx(); \
  /* q1 */ \
  LDA_(a1, ABc, 1); \
  if (tp1 < nt) stage(Ag, 128, tp1, shA + (NXTB) * 16384 + 8192); \
  barx(); MM_(a0, bq1, 0, 1); barx(); \
  /* q2 */ \
  if (tp2 < nt) stage(Bg, 0, tp2, shB + (CURB) * 8192); \
  barx(); MM_(a1, bq1, 1, 1); \
  if (tp2 < nt) vmw2(); else vmw0(); \
  barx(); \
  /* q3 */ \
  if (tp1 < nt) { LDA_(a0, ABn, 0); LDB_(BQF, BBn, 0); } \
  barx(); MM_(a1, BQU, 1, 0); barx(); \
} while (0)

  // prologue: B(0), A(0)-lo, A(0)-hi -> buf0 ; B(1) -> buf1
  stage(Bg, 0, 0, shB);
  stage(Ag, 0, 0, shA);
  stage(Ag, 128, 0, shA + 8192);
  if (nt > 1) { stage(Bg, 0, 1, shB + 8192); vmw2(); } else { vmw0(); }
  barx();
  LDA_(a0, AB0, 0);
  LDB_(bq0A, BB0, 0);

  for (int t = 0; t < nt; t += 2) {
    TILE_(t,     AB0, BB0, AB1, BB1, bq0A, bq0B, 0, 1);
    TILE_(t + 1, AB1, BB1, AB0, BB0, bq0B, bq0A, 1, 0);
  }
#undef TILE_
#undef MM_
#undef LDB_
#undef LDA_

  // epilogue
#pragma unroll
  for (int mi = 0; mi < 4; ++mi) {
#pragma unroll
    for (int ni = 0; ni < 4; ++ni) {
#pragma unroll
      for (int reg = 0; reg < 4; ++reg) {
        int grow = bm0 + wr * 64 + mi * 16 + quad * 4 + reg;
        int gcol = bn0 + wc * 64 + ni * 16 + row15;
        float v = acc[mi][ni][reg];
        if (MODE == 1) {
          if (gcol < nsplit) {
            Cx[(u32)grow * DI + (u32)gcol] = from_f<bf16>(v);
          } else {
            Cz[(u32)grow * DI + (u32)(gcol - nsplit)] = from_f<bf16>(fsilu(v));
          }
        } else {
          u32 o = (u32)grow * (u32)N + (u32)gcol;
          Cf[o] = v + R[o];
        }
      }
    }
  }
}

// ======== 128x128 MFMA GEMM (kept for dt_proj, K=64) ========
#define TM 128
#define TN 128
#define TK 32
#define LDK 40
template <int MODE>
__global__ __launch_bounds__(256) void gemm_mfma(const bf16* __restrict__ A,
                                                 const bf16* __restrict__ W,
                                                 int M, int N, int K,
                                                 bf16* __restrict__ Cx,
                                                 bf16* __restrict__ Cz, int nsplit,
                                                 float* __restrict__ Cf,
                                                 const float* __restrict__ R,
                                                 const float* __restrict__ bias) {
  __shared__ ushort Asm[TM][TK];   // linear — required by global_load_lds
  __shared__ ushort Bsm[TN][TK];
  int bm = blockIdx.y * TM, bn = blockIdx.x * TN;
  int tid = threadIdx.x;
  int lane = tid & 63, wave = tid >> 6;
  int wm = (wave & 1) * 64, wn = (wave >> 1) * 64;
  int row15 = lane & 15, quad = lane >> 4;

  int srow = lane >> 2;          // 0..15
  int scol = (lane & 3) * 8;     // 0,8,16,24
  int s0 = wave * 2, s1 = wave * 2 + 1;

  const ushort* Au = (const ushort*)A;
  const ushort* Wu = (const ushort*)W;
  const ushort* ag0 = Au + (size_t)(bm + s0 * 16 + srow) * K + scol;
  const ushort* ag1 = Au + (size_t)(bm + s1 * 16 + srow) * K + scol;
  const ushort* bg0 = Wu + (size_t)(bn + s0 * 16 + srow) * K + scol;
  const ushort* bg1 = Wu + (size_t)(bn + s1 * 16 + srow) * K + scol;
  ushort* la0 = &Asm[s0 * 16][0];
  ushort* la1 = &Asm[s1 * 16][0];
  ushort* lb0 = &Bsm[s0 * 16][0];
  ushort* lb1 = &Bsm[s1 * 16][0];

  floatx4 acc[4][4] = {};

  for (int k0 = 0; k0 < K; k0 += TK) {
    gload16(ag0 + k0, la0);
    gload16(ag1 + k0, la1);
    gload16(bg0 + k0, lb0);
    gload16(bg1 + k0, lb1);
    __syncthreads();
    short8 a_f[4], b_f[4];
#pragma unroll
    for (int i = 0; i < 4; ++i)
      a_f[i] = *(const short8*)&Asm[wm + i * 16 + row15][quad * 8];
#pragma unroll
    for (int j = 0; j < 4; ++j)
      b_f[j] = *(const short8*)&Bsm[wn + j * 16 + row15][quad * 8];
#pragma unroll
    for (int i = 0; i < 4; ++i)
#pragma unroll
      for (int j = 0; j < 4; ++j)
        acc[i][j] = __builtin_amdgcn_mfma_f32_16x16x32_bf16(a_f[i], b_f[j], acc[i][j], 0, 0, 0);
    __syncthreads();
  }
#pragma unroll
  for (int mi = 0; mi < 4; ++mi) {
#pragma unroll
    for (int ni = 0; ni < 4; ++ni) {
#pragma unroll
      for (int reg = 0; reg < 4; ++reg) {
        int grow = bm + wm + mi * 16 + quad * 4 + reg;
        int gcol = bn + wn + ni * 16 + row15;
        float v = acc[mi][ni][reg];
        if (MODE == 1) {
          if (gcol < nsplit) {
            Cx[(size_t)grow * DI + gcol] = from_f<bf16>(v);
          } else {
            Cz[(size_t)grow * DI + (gcol - nsplit)] = from_f<bf16>(fsilu(v));
          }
        } else if (MODE == 2) {
          size_t o = (size_t)grow * N + gcol;
          Cf[o] = v + R[o];
        } else {  // MODE 3: dt softplus
          float t = v + bias[gcol];
          float sp = (t > 20.f) ? t : __logf(1.f + __expf(t));
          Cx[(size_t)grow * N + gcol] = from_f<bf16>(sp);
        }
      }
    }
  }
}

// ======== x_proj split-K MFMA: xdbl[BL,96] += u[BL,2048-slice] @ xpw^T ========
#define XKS 128
__global__ __launch_bounds__(256) void xproj_k(const bf16* __restrict__ u,
                                               const bf16* __restrict__ w,
                                               float* __restrict__ xdbl) {
  __shared__ ushort Asm[128][LDK];
  __shared__ ushort Bsm[96][LDK];
  int kbase = blockIdx.x * XKS;
  int bm = blockIdx.y * 128;
  int tid = threadIdx.x;
  int lane = tid & 63, wave = tid >> 6;
  int row15 = lane & 15, quad = lane >> 4;
  int srow = tid >> 1, skoff = (tid & 1) * 16;

  floatx4 acc[2][6] = {};
  const ushort* Au = (const ushort*)u;
  const ushort* Wu = (const ushort*)w;
  for (int k0 = kbase; k0 < kbase + XKS; k0 += TK) {
    const ushort* ag = Au + (size_t)(bm + srow) * DI + k0 + skoff;
    *(short8*)&Asm[srow][skoff]     = *(const short8*)ag;
    *(short8*)&Asm[srow][skoff + 8] = *(const short8*)(ag + 8);
    if (tid < 192) {
      const ushort* wg = Wu + (size_t)srow * DI + k0 + skoff;
      *(short8*)&Bsm[srow][skoff]     = *(const short8*)wg;
      *(short8*)&Bsm[srow][skoff + 8] = *(const short8*)(wg + 8);
    }
    __syncthreads();
    short8 a_f[2], b_f[6];
#pragma unroll
    for (int i = 0; i < 2; ++i)
      a_f[i] = *(const short8*)&Asm[wave * 32 + i * 16 + row15][quad * 8];
#pragma unroll
    for (int j = 0; j < 6; ++j)
      b_f[j] = *(const short8*)&Bsm[j * 16 + row15][quad * 8];
#pragma unroll
    for (int i = 0; i < 2; ++i)
#pragma unroll
      for (int j = 0; j < 6; ++j)
        acc[i][j] = __builtin_amdgcn_mfma_f32_16x16x32_bf16(a_f[i], b_f[j], acc[i][j], 0, 0, 0);
    __syncthreads();
  }
#pragma unroll
  for (int mi = 0; mi < 2; ++mi)
#pragma unroll
    for (int nj = 0; nj < 6; ++nj)
#pragma unroll
      for (int reg = 0; reg < 4; ++reg) {
        int grow = bm + wave * 32 + mi * 16 + quad * 4 + reg;
        int gcol = nj * 16 + row15;
        atomicAdd(&xdbl[(size_t)grow * DXP + gcol], acc[mi][nj][reg]);
      }
}

// ---- extract xdbl[:, 0:64] -> bf16 [BL, 64] for the dt MFMA ----
__global__ __launch_bounds__(256) void dtex_k(const float* __restrict__ xdbl,
                                              bf16* __restrict__ dtin) {
  int i = blockIdx.x * 256 + threadIdx.x;  // BL*DR
  int r = i >> 6, c = i & 63;
  dtin[i] = from_f<bf16>(xdbl[(size_t)r * DXP + c]);
}

// ---------------- causal depthwise conv (K=4) + SiLU ----------------
#define TSTRIP 8
__global__ __launch_bounds__(256) void conv_silu_k(const bf16* __restrict__ xin,
                                                   const float* __restrict__ cw,
                                                   const float* __restrict__ cb,
                                                   bf16* __restrict__ u) {
  int blk = blockIdx.x;                   // NB * (SL/TSTRIP) blocks
  int b = blk >> 8;
  int l0 = (blk & 255) * TSTRIP;
  int c0 = threadIdx.x * 8;

  float4 cw4[8];
  const float4* cwp = (const float4*)cw;
#pragma unroll
  for (int j = 0; j < 8; ++j) cw4[j] = cwp[c0 + j];
  float cbv[8];
  {
    float4 cb0 = *(const float4*)&cb[c0];
    float4 cb1 = *(const float4*)&cb[c0 + 4];
    cbv[0] = cb0.x; cbv[1] = cb0.y; cbv[2] = cb0.z; cbv[3] = cb0.w;
    cbv[4] = cb1.x; cbv[5] = cb1.y; cbv[6] = cb1.z; cbv[7] = cb1.w;
  }

  const ushort* base = (const ushort*)xin + ((size_t)(b * SL + l0) * DI + c0);
  ushort* ubase = (ushort*)u + ((size_t)(b * SL + l0) * DI + c0);

  short8 zz = {};
  short8 w0 = zz, w1 = zz, w2 = zz;
  if (l0 >= 3) {
    w0 = *(const short8*)(base - 3 * DI);
    w1 = *(const short8*)(base - 2 * DI);
    w2 = *(const short8*)(base - 1 * DI);
  }
#pragma unroll
  for (int l = 0; l < TSTRIP; ++l) {
    short8 w3 = *(const short8*)(base + (ptrdiff_t)l * DI);
    short8 outv;
#pragma unroll
    for (int j = 0; j < 8; ++j) {
      float a = cbv[j]
              + bfbits2f((unsigned short)w0[j]) * cw4[j].x
              + bfbits2f((unsigned short)w1[j]) * cw4[j].y
              + bfbits2f((unsigned short)w2[j]) * cw4[j].z
              + bfbits2f((unsigned short)w3[j]) * cw4[j].w;
      outv[j] = f2bfbits(fsilu(a));
    }
    *(short8*)(ubase + (ptrdiff_t)l * DI) = outv;
    w0 = w1; w1 = w2; w2 = w3;
  }
}

// ======== chunked selective scan ========
__global__ __launch_bounds__(256) void scan_p1(const bf16* __restrict__ dts,
                                               const bf16* __restrict__ u,
                                               const float* __restrict__ xdbl,
                                               const float* __restrict__ A_log,
                                               float* __restrict__ Pbuf,
                                               float* __restrict__ Qbuf) {
  int bid = blockIdx.x;
  int b = bid >> 8;
  int c = (bid >> 3) & (NC - 1);
  int d = (bid & 7) * 256 + threadIdx.x;

  float A[DS], h[DS], P[DS];
#pragma unroll
  for (int s = 0; s < DS; ++s) {
    A[s] = -__expf(A_log[d * DS + s]);
    h[s] = 0.f; P[s] = 1.f;
  }
  size_t bl0 = (size_t)b * SL + c * CL;
  size_t base = bl0 * DI + d;
  size_t xb = bl0 * DXP + DR;
  for (int l = 0; l < CL; ++l) {
    float dtv = to_f(dts[base]);
    float uv = to_f(u[base]);
    float du = dtv * uv;
#pragma unroll
    for (int s = 0; s < DS; ++s) {
      float Bv = xdbl[xb + s];
      float dA = __expf(dtv * A[s]);
      h[s] = dA * h[s] + du * Bv;
      P[s] *= dA;
    }
    base += DI;
    xb += DXP;
  }
  size_t o = ((size_t)(b * NC + c) * DS) * DI + d;
#pragma unroll
  for (int s = 0; s < DS; ++s) {
    Pbuf[o + (size_t)s * DI] = P[s];
    Qbuf[o + (size_t)s * DI] = h[s];
  }
}

__global__ __launch_bounds__(256) void scan_p2(float* __restrict__ Pbuf,
                                               float* __restrict__ Qbuf) {
  int bid = blockIdx.x;
  int b = bid >> 7;
  int s = (bid >> 3) & (DS - 1);
  int d = (bid & 7) * 256 + threadIdx.x;
  float h = 0.f;
  for (int c = 0; c < NC; ++c) {
    size_t idx = ((size_t)((b * NC + c) * DS + s)) * DI + d;
    float Pv = Pbuf[idx];
    float qv = Qbuf[idx];
    Qbuf[idx] = h;
    h = Pv * h + qv;
  }
}

__global__ __launch_bounds__(256) void scan_p3(const bf16* __restrict__ dts,
                                               bf16* __restrict__ u,
                                               const float* __restrict__ xdbl,
                                               const float* __restrict__ A_log,
                                               const float* __restrict__ Dp,
                                               const bf16* __restrict__ g,
                                               const float* __restrict__ Qbuf) {
  int bid = blockIdx.x;
  int b = bid >> 8;
  int c = (bid >> 3) & (NC - 1);
  int d = (bid & 7) * 256 + threadIdx.x;

  float A[DS], h[DS];
  size_t o = ((size_t)(b * NC + c) * DS) * DI + d;
#pragma unroll
  for (int s = 0; s < DS; ++s) {
    A[s] = -__expf(A_log[d * DS + s]);
    h[s] = Qbuf[o + (size_t)s * DI];
  }
  float Dd = Dp[d];
  size_t bl0 = (size_t)b * SL + c * CL;
  size_t base = bl0 * DI + d;
  size_t xb = bl0 * DXP + DR;
  for (int l = 0; l < CL; ++l) {
    float dtv = to_f(dts[base]);
    float uv = to_f(u[base]);
    float gv = to_f(g[base]);
    float du = dtv * uv;
    float p0 = 0.f, p1 = 0.f, p2 = 0.f, p3 = 0.f;
#pragma unroll
    for (int s = 0; s < DS; s += 4) {
      float dA0 = __expf(dtv * A[s + 0]);
      float dA1 = __expf(dtv * A[s + 1]);
      float dA2 = __expf(dtv * A[s + 2]);
      float dA3 = __expf(dtv * A[s + 3]);
      h[s + 0] = dA0 * h[s + 0] + du * xdbl[xb + s + 0];
      h[s + 1] = dA1 * h[s + 1] + du * xdbl[xb + s + 1];
      h[s + 2] = dA2 * h[s + 2] + du * xdbl[xb + s + 2];
      h[s + 3] = dA3 * h[s + 3] + du * xdbl[xb + s + 3];
      p0 += h[s + 0] * xdbl[xb + DS + s + 0];
      p1 += h[s + 1] * xdbl[xb + DS + s + 1];
      p2 += h[s + 2] * xdbl[xb + DS + s + 2];
      p3 += h[s + 3] * xdbl[xb + DS + s + 3];
    }
    float yv = ((p0 + p1) + (p2 + p3)) + Dd * uv;
    u[base] = from_f<bf16>(yv * gv);
    base += DI;
    xb += DXP;
  }
}

extern "C" void kernel_launch(void* const* d_in, const int* in_sizes, int n_in,
                              void* d_out, int out_size, void* d_ws, size_t ws_size,
                              hipStream_t stream) {
  const float* x        = (const float*)d_in[0];
  const float* norm_w   = (const float*)d_in[1];
  const float* in_projw = (const float*)d_in[2];
  const float* conv_w   = (const float*)d_in[3];
  const float* conv_b   = (const float*)d_in[4];
  const float* x_projw  = (const float*)d_in[5];
  const float* dt_projw = (const float*)d_in[6];
  const float* dt_projb = (const float*)d_in[7];
  const float* A_log    = (const float*)d_in[8];
  const float* Dp       = (const float*)d_in[9];
  const float* out_projw= (const float*)d_in[10];
  float* out = (float*)d_out;

  // ---- workspace (~104 MiB), lifetime overlays ----
  char* wsb = (char*)d_ws;
  bf16* x_buf  = (bf16*)wsb;                           // x half; later dt; later opw_bf
  bf16* z_buf  = (bf16*)(wsb + (size_t)BL * DI * 2);   // silu(z) gate
  bf16* u_buf  = (bf16*)(wsb + (size_t)BL * DI * 4);   // xnorm_bf (early) then u/y
  char* ovl    = wsb + (size_t)BL * DI * 6;            // 8 MiB overlay
  bf16* ipw_bf = (bf16*)ovl;                           // phase A: in_proj w bf16 (8 MiB)
  // phase B overlay (after in_proj):
  float* xdbl   = (float*)ovl;                                 // 3 MiB
  bf16*  xpw_bf = (bf16*)(ovl + 3145728);                      // 0.375 MiB
  bf16*  dtw_bf = (bf16*)(ovl + 3538944);                      // 0.25 MiB
  bf16*  dtin_bf= (bf16*)(ovl + 3801088);                      // 1 MiB
  bf16* xnorm_bf = u_buf;
  bf16* dt_buf   = x_buf;   // x half dead after conv
  bf16* opw_bf   = x_buf;   // dt dead after scan p3
  float* Pbuf = out;        // d_out scratch until out_proj
  float* Qbuf = out + (size_t)NB * NC * DS * DI;

  // 1. in_proj weights -> bf16
  f2b_k<<<(2 * DI * DM) / 256, 256, 0, stream>>>(in_projw, ipw_bf, 2 * DI * DM);
  // 2. RMSNorm -> bf16
  rmsnorm_k<<<BL, 256, 0, stream>>>(x, norm_w, xnorm_bf);
  // 3. in_proj (256x256 8-phase MFMA): x half -> x_buf ; z half silu -> z_buf
  gemm256<1><<<(BL / 256) * (2 * DI / 256), 512, 0, stream>>>(
      xnorm_bf, ipw_bf, BL, 2 * DI, DM, x_buf, z_buf, DI, nullptr, nullptr);
  // 4. causal conv + silu -> u_buf (time-strip, register sliding window)
  conv_silu_k<<<NB * (SL / TSTRIP), 256, 0, stream>>>(x_buf, conv_w, conv_b, u_buf);
  // 5. x_proj: zero xdbl, convert weights, split-K MFMA with atomic accumulate
  hipMemsetAsync(xdbl, 0, (size_t)BL * DXP * sizeof(float), stream);
  f2b_k<<<(DXP * DI + 255) / 256, 256, 0, stream>>>(x_projw, xpw_bf, DXP * DI);
  f2b_k<<<(DI * DR) / 256, 256, 0, stream>>>(dt_projw, dtw_bf, DI * DR);
  xproj_k<<<dim3(DI / XKS, BL / 128), 256, 0, stream>>>(u_buf, xpw_bf, xdbl);
  // 6. dt input slice -> bf16, dt_proj (MFMA, fused bias+softplus) -> dt_buf
  dtex_k<<<(BL * DR) / 256, 256, 0, stream>>>(xdbl, dtin_bf);
  gemm_mfma<3><<<dim3(DI / TN, BL / TM), 256, 0, stream>>>(
      dtin_bf, dtw_bf, BL, DI, DR, dt_buf, nullptr, 0, nullptr, nullptr, dt_projb);
  // 7. chunked scan
  scan_p1<<<NB * NC * (DI / 256), 256, 0, stream>>>(dt_buf, u_buf, xdbl, A_log, Pbuf, Qbuf);
  scan_p2<<<NB * DS * (DI / 256), 256, 0, stream>>>(Pbuf, Qbuf);
  scan_p3<<<NB * NC * (DI / 256), 256, 0, stream>>>(dt_buf, u_buf, xdbl, A_log, Dp, z_buf, Qbuf);
  // 8. out_proj weights -> bf16, out_proj (256x128 pipelined, full grid) + residual
  f2b_k<<<(DM * DI) / 256, 256, 0, stream>>>(out_projw, opw_bf, DM * DI);
  gemm_np<2><<<(BL / 256) * (DM / 128), 512, 0, stream>>>(
      u_buf, opw_bf, BL, DM, DI, nullptr, nullptr, 0, out, x);
}

// Round 6
// 436.444 us; speedup vs baseline: 1.1532x; 1.0678x over previous
//
#include <hip/hip_runtime.h>
#include <hip/hip_bf16.h>
#include <math.h>

#define DM 1024   // d_model
#define DI 2048   // d_inner
#define DS 16     // d_state
#define DC 4      // d_conv
#define DR 64     // dt_rank
#define NB 4      // batch
#define SL 2048   // seqlen
#define BL (NB * SL)        // 8192 rows
#define DXP (DR + 2 * DS)   // 96
#define NC 32               // scan chunks
#define CL (SL / NC)        // 64 steps per chunk
#define XNS 8               // x_proj K-splits (partial buffers, no atomics)

typedef __hip_bfloat16 bf16;
typedef __attribute__((ext_vector_type(8))) short short8;
typedef __attribute__((ext_vector_type(4))) float floatx4;
typedef unsigned int u32;

__device__ __forceinline__ float to_f(float v) { return v; }
__device__ __forceinline__ float to_f(bf16 v) { return __bfloat162float(v); }
template <typename T> __device__ __forceinline__ T from_f(float v);
template <> __device__ __forceinline__ float from_f<float>(float v) { return v; }
template <> __device__ __forceinline__ bf16 from_f<bf16>(float v) { return __float2bfloat16(v); }

__device__ __forceinline__ float bfbits2f(unsigned short u) {
  u32 b = ((u32)u) << 16;
  return __builtin_bit_cast(float, b);
}
__device__ __forceinline__ short f2bfbits(float v) {
  bf16 b = __float2bfloat16(v);
  return __builtin_bit_cast(short, b);
}
// fast silu: x * rcp(1+e^-x)  (v_rcp_f32, ~1 ulp — fine for bf16 outputs)
__device__ __forceinline__ float fsilu(float v) {
  return v * __builtin_amdgcn_rcpf(1.f + __expf(-v));
}

// async global->LDS, 16B per lane. LDS dest = wave-uniform base + lane*16.
__device__ __forceinline__ void gload16(const ushort* g, ushort* l) {
  __builtin_amdgcn_global_load_lds((const __attribute__((address_space(1))) void*)g,
                                   (__attribute__((address_space(3))) void*)l,
                                   16, 0, 0);
}

__device__ __forceinline__ void vmw4() { asm volatile("s_waitcnt vmcnt(4)" ::: "memory"); }
__device__ __forceinline__ void vmw2() { asm volatile("s_waitcnt vmcnt(2)" ::: "memory"); }
__device__ __forceinline__ void vmw0() { asm volatile("s_waitcnt vmcnt(0)" ::: "memory"); }
// raw barrier (NO implicit vmcnt drain) with compiler-only memory fences so
// LDS reads/stages can't migrate across phases.
__device__ __forceinline__ void barx() {
  asm volatile("" ::: "memory");
  __builtin_amdgcn_s_barrier();
  asm volatile("" ::: "memory");
}

// ---------------- fp32 -> bf16 conversion ----------------
__global__ __launch_bounds__(256) void f2b_k(const float* __restrict__ src,
                                             bf16* __restrict__ dst, int n) {
  int i = blockIdx.x * 256 + threadIdx.x;
  if (i < n) dst[i] = from_f<bf16>(src[i]);
}

// ---------------- RMSNorm (bf16 out) ----------------
__global__ __launch_bounds__(256) void rmsnorm_k(const float* __restrict__ x,
                                                 const float* __restrict__ w,
                                                 bf16* __restrict__ o) {
  int row = blockIdx.x;
  const float* xr = x + (size_t)row * DM;
  float ss = 0.f;
  for (int i = threadIdx.x; i < DM; i += 256) { float v = xr[i]; ss += v * v; }
  for (int off = 32; off > 0; off >>= 1) ss += __shfl_down(ss, off);
  __shared__ float sred[4];
  __shared__ float sscale;
  if ((threadIdx.x & 63) == 0) sred[threadIdx.x >> 6] = ss;
  __syncthreads();
  if (threadIdx.x == 0) {
    float t = sred[0] + sred[1] + sred[2] + sred[3];
    sscale = rsqrtf(t / (float)DM + 1.1920929e-7f);
  }
  __syncthreads();
  float sc = sscale;
  bf16* orow = o + (size_t)row * DM;
  for (int i = threadIdx.x; i < DM; i += 256) orow[i] = from_f<bf16>(xr[i] * sc * w[i]);
}

// ======== 256x256 8-phase pipelined MFMA GEMM (in_proj) ========
// st_16x32 LDS swizzle (T2), half-tile prefetch with counted vmcnt (T3+T4),
// setprio (T5).  R6: N-fastest XCD swizzle — each XCD owns a 4-M-tile chunk
// (A slice 2 MB, L2-resident) swept across all N, cutting A re-fetch.
template <int MODE>
__global__ __launch_bounds__(512, 1) void gemm256(const bf16* __restrict__ A,
                                                  const bf16* __restrict__ W,
                                                  int M, int N, int K,
                                                  bf16* __restrict__ Cx,
                                                  bf16* __restrict__ Cz, int nsplit,
                                                  float* __restrict__ Cf,
                                                  const float* __restrict__ R) {
  __shared__ ushort SH[65536];   // 128 KiB: A @ 0..64K, B @ 64K..128K (bytes)
  const int tid = threadIdx.x;
  const int lane = tid & 63, wv = tid >> 6;
  const int wr = wv >> 2, wc = wv & 3;
  const int row15 = lane & 15, quad = lane >> 4;

  // XCD-aware block swizzle, N-fastest within each XCD chunk
  int ntm = M >> 8, ntn = N >> 8, nwg = ntm * ntn;
  int bid = blockIdx.x;
  int swz = (bid & 7) * (nwg >> 3) + (bid >> 3);
  int bm0 = (swz / ntn) << 8, bn0 = (swz % ntn) << 8;

  const int nt = K >> 6;   // K-tiles
  const ushort* Au = (const ushort*)A;
  const ushort* Wu = (const ushort*)W;

  // staging: lane's inverse-swizzled source chunk (involution in chunk space)
  const int w4u = lane ^ (((lane >> 5) & 1) << 1);
  // fragment-read swizzled byte offset within a 1024B subtile
  const int Wsw = (((row15 << 6) | (quad << 4)) ^ (((row15 >> 3) & 1) << 5));
  const char* SHb = (const char*)SH;
  // ds_read base byte offsets (cur encoded in the two variants)
  const int Abase0 = (wr << 14) + Wsw;
  const int Abase1 = 32768 + (wr << 14) + Wsw;
  const int Bbase0 = 65536 + ((wc >> 1) << 14) + ((wc & 1) << 13) + Wsw;
  const int Bbase1 = Bbase0 + 32768;

  auto stageA = [&](int tt, int half, int buf) {
    const ushort* g = Au + (size_t)(bm0 + half * 128) * K + tt * 64;
    char* lds = (char*)SH + (size_t)(buf * 2 + half) * 16384;
#pragma unroll
    for (int i = 0; i < 2; ++i) {
      int sub = wv + i * 8;
      int r = ((sub >> 1) << 4) | (w4u >> 2);
      int ce = ((sub & 1) << 5) | ((w4u & 3) << 3);
      gload16(g + (size_t)r * K + ce, (ushort*)(lds + sub * 1024));
    }
  };
  auto stageB = [&](int tt, int half, int buf) {
    const ushort* g = Wu + (size_t)(bn0 + half * 128) * K + tt * 64;
    char* lds = (char*)SH + 65536 + (size_t)(buf * 2 + half) * 16384;
#pragma unroll
    for (int i = 0; i < 2; ++i) {
      int sub = wv + i * 8;
      int r = ((sub >> 1) << 4) | (w4u >> 2);
      int ce = ((sub & 1) << 5) | ((w4u & 3) << 3);
      gload16(g + (size_t)r * K + ce, (ushort*)(lds + sub * 1024));
    }
  };

  short8 a_f[4][2], bq[2][2][2];   // bq[nh][ni][kk]; bq[0] retained q0->q3
  floatx4 acc[8][4] = {};

#define LDA_(base, mh) do { _Pragma("unroll") for (int mi = 0; mi < 4; ++mi) \
  { _Pragma("unroll") for (int kk = 0; kk < 2; ++kk) \
    a_f[mi][kk] = *(const short8*)(SHb + (base) + ((((mh)*4 + mi)*2 + kk) << 10)); } } while (0)
#define LDB_(base, nh) do { _Pragma("unroll") for (int ni = 0; ni < 2; ++ni) \
  { _Pragma("unroll") for (int kk = 0; kk < 2; ++kk) \
    bq[nh][ni][kk] = *(const short8*)(SHb + (base) + (((((nh)*2 + ni)*2 + kk)) << 10)); } } while (0)
#define MM_(mh, nh) do { __builtin_amdgcn_s_setprio(1); \
  _Pragma("unroll") for (int mi = 0; mi < 4; ++mi) \
  { _Pragma("unroll") for (int ni = 0; ni < 2; ++ni) \
    { _Pragma("unroll") for (int kk = 0; kk < 2; ++kk) \
      acc[(mh)*4+mi][(nh)*2+ni] = __builtin_amdgcn_mfma_f32_16x16x32_bf16( \
          a_f[mi][kk], bq[nh][ni][kk], acc[(mh)*4+mi][(nh)*2+ni], 0, 0, 0); } } \
  __builtin_amdgcn_s_setprio(0); } while (0)

#define TILE_(t, AB, BB, curbuf, nxtbuf) do { \
  int tp1 = (t) + 1, tp2 = (t) + 2; \
  LDA_(AB, 0); LDB_(BB, 0); \
  if (tp1 < nt) stageA(tp1, 0, nxtbuf); \
  barx(); MM_(0, 0); barx(); \
  LDB_(BB, 1); \
  if (tp1 < nt) stageA(tp1, 1, nxtbuf); \
  barx(); MM_(0, 1); barx(); \
  LDA_(AB, 1); \
  if (tp2 < nt) stageB(tp2, 0, curbuf); \
  barx(); MM_(1, 1); barx(); \
  if (tp2 < nt) stageB(tp2, 1, curbuf); \
  barx(); MM_(1, 0); \
  if (tp2 < nt) vmw4(); else vmw0(); \
  barx(); \
} while (0)

  // prologue: tile0's 4 halves + tile1's B halves (6 halves = 12 loads)
  stageB(0, 0, 0); stageB(0, 1, 0); stageA(0, 0, 0); stageA(0, 1, 0);
  stageB(1, 0, 1); stageB(1, 1, 1);
  vmw4();   // tile0 complete; tile1's B halves (4 loads) in flight
  barx();

  for (int t = 0; t < nt; t += 2) {
    TILE_(t, Abase0, Bbase0, 0, 1);
    TILE_(t + 1, Abase1, Bbase1, 1, 0);
  }
#undef TILE_
#undef MM_
#undef LDB_
#undef LDA_

  // epilogue
#pragma unroll
  for (int mi8 = 0; mi8 < 8; ++mi8) {
#pragma unroll
    for (int ni4 = 0; ni4 < 4; ++ni4) {
#pragma unroll
      for (int reg = 0; reg < 4; ++reg) {
        int grow = bm0 + wr * 128 + mi8 * 16 + quad * 4 + reg;
        int gcol = bn0 + wc * 64 + ni4 * 16 + row15;
        float v = acc[mi8][ni4][reg];
        if (MODE == 1) {
          if (gcol < nsplit) {
            Cx[(size_t)grow * DI + gcol] = from_f<bf16>(v);
          } else {
            Cz[(size_t)grow * DI + (gcol - nsplit)] = from_f<bf16>(fsilu(v));
          }
        } else {
          size_t o = (size_t)grow * N + gcol;
          Cf[o] = v + R[o];
        }
      }
    }
  }
}

// ======== 256x128 pipelined MFMA GEMM (out_proj; full grid at N=1024) ====
// 8 waves (4M x 2N), per-wave 64x64; fragment pre-read pipeline; LDS 96 KiB.
// R6: N-fastest XCD swizzle (same rationale as gemm256).
template <int MODE>
__global__ __launch_bounds__(512, 1) void gemm_np(const bf16* __restrict__ A,
                                                  const bf16* __restrict__ W,
                                                  int M, int N, int K,
                                                  bf16* __restrict__ Cx,
                                                  bf16* __restrict__ Cz, int nsplit,
                                                  float* __restrict__ Cf,
                                                  const float* __restrict__ R) {
  __shared__ ushort SH[49152];   // 96 KiB
  const int tid = threadIdx.x;
  const int lane = tid & 63, wv = tid >> 6;
  const int wr = wv >> 1, wc = wv & 1;          // 4M x 2N wave grid
  const int row15 = lane & 15, quad = lane >> 4;

  // XCD-aware block swizzle, N-fastest within each XCD chunk
  int ntm = M >> 8, ntn = N >> 7, nwg = ntm * ntn;
  int bid = blockIdx.x;
  int swz = (bid & 7) * (nwg >> 3) + (bid >> 3);
  int bm0 = (swz / ntn) << 8, bn0 = (swz % ntn) << 7;

  const int nt = K >> 6;   // K-tiles (even)
  const ushort* Au = (const ushort*)A;
  const ushort* Wu = (const ushort*)W;
  const ushort* Ag = Au + (u32)bm0 * (u32)K;
  const ushort* Bg = Wu + (u32)bn0 * (u32)K;

  // staging coords: lane's inverse-swizzled chunk (st_16x32 involution)
  const int w4u = lane ^ (((lane >> 5) & 1) << 1);
  const int sub0 = wv, sub1 = wv + 8;
  const int r0 = ((sub0 >> 1) << 4) | (w4u >> 2);
  const int c0 = ((sub0 & 1) << 5) | ((w4u & 3) << 3);
  const int r1 = ((sub1 >> 1) << 4) | (w4u >> 2);
  const int c1 = ((sub1 & 1) << 5) | ((w4u & 3) << 3);
  ushort* shA = (ushort*)SH;            // 2 bufs x 16384 ushorts
  ushort* shB = (ushort*)SH + 32768;    // 2 bufs x 8192 ushorts

  auto stage = [&](const ushort* gbase, int rowoff, int tt, ushort* lbase) {
    gload16(gbase + (u32)(rowoff + r0) * (u32)K + (u32)(tt * 64 + c0), lbase + (sub0 << 9));
    gload16(gbase + (u32)(rowoff + r1) * (u32)K + (u32)(tt * 64 + c1), lbase + (sub1 << 9));
  };

  // fragment-read swizzled byte offset within a 1024B subtile
  const int Wsw = (((row15 << 6) | (quad << 4)) ^ (((row15 >> 3) & 1) << 5));
  const char* SHb = (const char*)SH;
  const int AB0 = (wr << 13) + Wsw;
  const int AB1 = 32768 + AB0;
  const int BB0 = 65536 + (wc << 13) + Wsw;
  const int BB1 = BB0 + 16384;

  short8 a0[2][2], a1[2][2], bq0A[2][2], bq0B[2][2], bq1[2][2];
  floatx4 acc[4][4] = {};

#define LDA_(dst, base, mh) do { _Pragma("unroll") for (int i_ = 0; i_ < 2; ++i_) \
  { _Pragma("unroll") for (int kk = 0; kk < 2; ++kk) \
    dst[i_][kk] = *(const short8*)(SHb + (base) + ((((mh)*2 + i_)*2 + kk) << 10)); } } while (0)
#define LDB_(dst, base, nh) do { _Pragma("unroll") for (int j_ = 0; j_ < 2; ++j_) \
  { _Pragma("unroll") for (int kk = 0; kk < 2; ++kk) \
    dst[j_][kk] = *(const short8*)(SHb + (base) + ((((nh)*2 + j_)*2 + kk) << 10)); } } while (0)
#define MM_(aset, bset, mh, nh) do { __builtin_amdgcn_s_setprio(1); \
  _Pragma("unroll") for (int i_ = 0; i_ < 2; ++i_) \
  { _Pragma("unroll") for (int j_ = 0; j_ < 2; ++j_) \
    { _Pragma("unroll") for (int kk = 0; kk < 2; ++kk) \
      acc[(mh)*2+i_][(nh)*2+j_] = __builtin_amdgcn_mfma_f32_16x16x32_bf16( \
          aset[i_][kk], bset[j_][kk], acc[(mh)*2+i_][(nh)*2+j_], 0, 0, 0); } } \
  __builtin_amdgcn_s_setprio(0); } while (0)

#define TILE_(t, ABc, BBc, ABn, BBn, BQU, BQF, CURB, NXTB) do { \
  int tp1 = (t) + 1, tp2 = (t) + 2; \
  /* q0 */ \
  LDB_(bq1, BBc, 1); \
  if (tp1 < nt) stage(Ag, 0, tp1, shA + (NXTB) * 16384); \
  barx(); MM_(a0, BQU, 0, 0); barx(); \
  /* q1 */ \
  LDA_(a1, ABc, 1); \
  if (tp1 < nt) stage(Ag, 128, tp1, shA + (NXTB) * 16384 + 8192); \
  barx(); MM_(a0, bq1, 0, 1); barx(); \
  /* q2 */ \
  if (tp2 < nt) stage(Bg, 0, tp2, shB + (CURB) * 8192); \
  barx(); MM_(a1, bq1, 1, 1); \
  if (tp2 < nt) vmw2(); else vmw0(); \
  barx(); \
  /* q3 */ \
  if (tp1 < nt) { LDA_(a0, ABn, 0); LDB_(BQF, BBn, 0); } \
  barx(); MM_(a1, BQU, 1, 0); barx(); \
} while (0)

  // prologue: B(0), A(0)-lo, A(0)-hi -> buf0 ; B(1) -> buf1
  stage(Bg, 0, 0, shB);
  stage(Ag, 0, 0, shA);
  stage(Ag, 128, 0, shA + 8192);
  if (nt > 1) { stage(Bg, 0, 1, shB + 8192); vmw2(); } else { vmw0(); }
  barx();
  LDA_(a0, AB0, 0);
  LDB_(bq0A, BB0, 0);

  for (int t = 0; t < nt; t += 2) {
    TILE_(t,     AB0, BB0, AB1, BB1, bq0A, bq0B, 0, 1);
    TILE_(t + 1, AB1, BB1, AB0, BB0, bq0B, bq0A, 1, 0);
  }
#undef TILE_
#undef MM_
#undef LDB_
#undef LDA_

  // epilogue
#pragma unroll
  for (int mi = 0; mi < 4; ++mi) {
#pragma unroll
    for (int ni = 0; ni < 4; ++ni) {
#pragma unroll
      for (int reg = 0; reg < 4; ++reg) {
        int grow = bm0 + wr * 64 + mi * 16 + quad * 4 + reg;
        int gcol = bn0 + wc * 64 + ni * 16 + row15;
        float v = acc[mi][ni][reg];
        if (MODE == 1) {
          if (gcol < nsplit) {
            Cx[(u32)grow * DI + (u32)gcol] = from_f<bf16>(v);
          } else {
            Cz[(u32)grow * DI + (u32)(gcol - nsplit)] = from_f<bf16>(fsilu(v));
          }
        } else {
          u32 o = (u32)grow * (u32)N + (u32)gcol;
          Cf[o] = v + R[o];
        }
      }
    }
  }
}

// ======== 128x128 MFMA GEMM (kept for dt_proj, K=64) ========
#define TM 128
#define TN 128
#define TK 32
#define LDK 40
template <int MODE>
__global__ __launch_bounds__(256) void gemm_mfma(const bf16* __restrict__ A,
                                                 const bf16* __restrict__ W,
                                                 int M, int N, int K,
                                                 bf16* __restrict__ Cx,
                                                 bf16* __restrict__ Cz, int nsplit,
                                                 float* __restrict__ Cf,
                                                 const float* __restrict__ R,
                                                 const float* __restrict__ bias) {
  __shared__ ushort Asm[TM][TK];   // linear — required by global_load_lds
  __shared__ ushort Bsm[TN][TK];
  int bm = blockIdx.y * TM, bn = blockIdx.x * TN;
  int tid = threadIdx.x;
  int lane = tid & 63, wave = tid >> 6;
  int wm = (wave & 1) * 64, wn = (wave >> 1) * 64;
  int row15 = lane & 15, quad = lane >> 4;

  int srow = lane >> 2;          // 0..15
  int scol = (lane & 3) * 8;     // 0,8,16,24
  int s0 = wave * 2, s1 = wave * 2 + 1;

  const ushort* Au = (const ushort*)A;
  const ushort* Wu = (const ushort*)W;
  const ushort* ag0 = Au + (size_t)(bm + s0 * 16 + srow) * K + scol;
  const ushort* ag1 = Au + (size_t)(bm + s1 * 16 + srow) * K + scol;
  const ushort* bg0 = Wu + (size_t)(bn + s0 * 16 + srow) * K + scol;
  const ushort* bg1 = Wu + (size_t)(bn + s1 * 16 + srow) * K + scol;
  ushort* la0 = &Asm[s0 * 16][0];
  ushort* la1 = &Asm[s1 * 16][0];
  ushort* lb0 = &Bsm[s0 * 16][0];
  ushort* lb1 = &Bsm[s1 * 16][0];

  floatx4 acc[4][4] = {};

  for (int k0 = 0; k0 < K; k0 += TK) {
    gload16(ag0 + k0, la0);
    gload16(ag1 + k0, la1);
    gload16(bg0 + k0, lb0);
    gload16(bg1 + k0, lb1);
    __syncthreads();
    short8 a_f[4], b_f[4];
#pragma unroll
    for (int i = 0; i < 4; ++i)
      a_f[i] = *(const short8*)&Asm[wm + i * 16 + row15][quad * 8];
#pragma unroll
    for (int j = 0; j < 4; ++j)
      b_f[j] = *(const short8*)&Bsm[wn + j * 16 + row15][quad * 8];
#pragma unroll
    for (int i = 0; i < 4; ++i)
#pragma unroll
      for (int j = 0; j < 4; ++j)
        acc[i][j] = __builtin_amdgcn_mfma_f32_16x16x32_bf16(a_f[i], b_f[j], acc[i][j], 0, 0, 0);
    __syncthreads();
  }
#pragma unroll
  for (int mi = 0; mi < 4; ++mi) {
#pragma unroll
    for (int ni = 0; ni < 4; ++ni) {
#pragma unroll
      for (int reg = 0; reg < 4; ++reg) {
        int grow = bm + wm + mi * 16 + quad * 4 + reg;
        int gcol = bn + wn + ni * 16 + row15;
        float v = acc[mi][ni][reg];
        if (MODE == 1) {
          if (gcol < nsplit) {
            Cx[(size_t)grow * DI + gcol] = from_f<bf16>(v);
          } else {
            Cz[(size_t)grow * DI + (gcol - nsplit)] = from_f<bf16>(fsilu(v));
          }
        } else if (MODE == 2) {
          size_t o = (size_t)grow * N + gcol;
          Cf[o] = v + R[o];
        } else {  // MODE 3: dt softplus
          float t = v + bias[gcol];
          float sp = (t > 20.f) ? t : __logf(1.f + __expf(t));
          Cx[(size_t)grow * N + gcol] = from_f<bf16>(sp);
        }
      }
    }
  }
}

// ======== x_proj split-K MFMA, partial buffers (no atomics) ========
// Ppart[split][BL][96] fp32; split s covers K slice [s*256, (s+1)*256).
__global__ __launch_bounds__(256) void xproj_k(const bf16* __restrict__ u,
                                               const bf16* __restrict__ w,
                                               float* __restrict__ Ppart) {
  __shared__ ushort Asm[128][LDK];
  __shared__ ushort Bsm[96][LDK];
  int kbase = blockIdx.x * (DI / XNS);
  int bm = blockIdx.y * 128;
  int tid = threadIdx.x;
  int lane = tid & 63, wave = tid >> 6;
  int row15 = lane & 15, quad = lane >> 4;
  int srow = tid >> 1, skoff = (tid & 1) * 16;

  floatx4 acc[2][6] = {};
  const ushort* Au = (const ushort*)u;
  const ushort* Wu = (const ushort*)w;
  for (int k0 = kbase; k0 < kbase + (DI / XNS); k0 += TK) {
    const ushort* ag = Au + (size_t)(bm + srow) * DI + k0 + skoff;
    *(short8*)&Asm[srow][skoff]     = *(const short8*)ag;
    *(short8*)&Asm[srow][skoff + 8] = *(const short8*)(ag + 8);
    if (tid < 192) {
      const ushort* wg = Wu + (size_t)srow * DI + k0 + skoff;
      *(short8*)&Bsm[srow][skoff]     = *(const short8*)wg;
      *(short8*)&Bsm[srow][skoff + 8] = *(const short8*)(wg + 8);
    }
    __syncthreads();
    short8 a_f[2], b_f[6];
#pragma unroll
    for (int i = 0; i < 2; ++i)
      a_f[i] = *(const short8*)&Asm[wave * 32 + i * 16 + row15][quad * 8];
#pragma unroll
    for (int j = 0; j < 6; ++j)
      b_f[j] = *(const short8*)&Bsm[j * 16 + row15][quad * 8];
#pragma unroll
    for (int i = 0; i < 2; ++i)
#pragma unroll
      for (int j = 0; j < 6; ++j)
        acc[i][j] = __builtin_amdgcn_mfma_f32_16x16x32_bf16(a_f[i], b_f[j], acc[i][j], 0, 0, 0);
    __syncthreads();
  }
  float* P = Ppart + (size_t)blockIdx.x * ((size_t)BL * DXP);
#pragma unroll
  for (int mi = 0; mi < 2; ++mi)
#pragma unroll
    for (int nj = 0; nj < 6; ++nj)
#pragma unroll
      for (int reg = 0; reg < 4; ++reg) {
        int grow = bm + wave * 32 + mi * 16 + quad * 4 + reg;
        int gcol = nj * 16 + row15;
        P[(size_t)grow * DXP + gcol] = acc[mi][nj][reg];
      }
}

// ---- reduce partials -> xdbl fp32; also emit dtin bf16 (fuses old dtex_k) ----
__global__ __launch_bounds__(256) void xred_k(const float* __restrict__ Ppart,
                                              float* __restrict__ xdbl,
                                              bf16* __restrict__ dtin) {
  int i = blockIdx.x * 256 + threadIdx.x;   // BL * DXP total
  float s = 0.f;
#pragma unroll
  for (int p = 0; p < XNS; ++p) s += Ppart[(size_t)p * ((size_t)BL * DXP) + i];
  xdbl[i] = s;
  int r = i / DXP, c = i - r * DXP;
  if (c < DR) dtin[r * DR + c] = from_f<bf16>(s);
}

// ---------------- causal depthwise conv (K=4) + SiLU ----------------
#define TSTRIP 8
__global__ __launch_bounds__(256) void conv_silu_k(const bf16* __restrict__ xin,
                                                   const float* __restrict__ cw,
                                                   const float* __restrict__ cb,
                                                   bf16* __restrict__ u) {
  int blk = blockIdx.x;                   // NB * (SL/TSTRIP) blocks
  int b = blk >> 8;
  int l0 = (blk & 255) * TSTRIP;
  int c0 = threadIdx.x * 8;

  float4 cw4[8];
  const float4* cwp = (const float4*)cw;
#pragma unroll
  for (int j = 0; j < 8; ++j) cw4[j] = cwp[c0 + j];
  float cbv[8];
  {
    float4 cb0 = *(const float4*)&cb[c0];
    float4 cb1 = *(const float4*)&cb[c0 + 4];
    cbv[0] = cb0.x; cbv[1] = cb0.y; cbv[2] = cb0.z; cbv[3] = cb0.w;
    cbv[4] = cb1.x; cbv[5] = cb1.y; cbv[6] = cb1.z; cbv[7] = cb1.w;
  }

  const ushort* base = (const ushort*)xin + ((size_t)(b * SL + l0) * DI + c0);
  ushort* ubase = (ushort*)u + ((size_t)(b * SL + l0) * DI + c0);

  short8 zz = {};
  short8 w0 = zz, w1 = zz, w2 = zz;
  if (l0 >= 3) {
    w0 = *(const short8*)(base - 3 * DI);
    w1 = *(const short8*)(base - 2 * DI);
    w2 = *(const short8*)(base - 1 * DI);
  }
#pragma unroll
  for (int l = 0; l < TSTRIP; ++l) {
    short8 w3 = *(const short8*)(base + (ptrdiff_t)l * DI);
    short8 outv;
#pragma unroll
    for (int j = 0; j < 8; ++j) {
      float a = cbv[j]
              + bfbits2f((unsigned short)w0[j]) * cw4[j].x
              + bfbits2f((unsigned short)w1[j]) * cw4[j].y
              + bfbits2f((unsigned short)w2[j]) * cw4[j].z
              + bfbits2f((unsigned short)w3[j]) * cw4[j].w;
      outv[j] = f2bfbits(fsilu(a));
    }
    *(short8*)(ubase + (ptrdiff_t)l * DI) = outv;
    w0 = w1; w1 = w2; w2 = w3;
  }
}

// ======== chunked selective scan ========
__global__ __launch_bounds__(256) void scan_p1(const bf16* __restrict__ dts,
                                               const bf16* __restrict__ u,
                                               const float* __restrict__ xdbl,
                                               const float* __restrict__ A_log,
                                               float* __restrict__ Pbuf,
                                               float* __restrict__ Qbuf) {
  int bid = blockIdx.x;
  int b = bid >> 8;
  int c = (bid >> 3) & (NC - 1);
  int d = (bid & 7) * 256 + threadIdx.x;

  float A[DS], h[DS], P[DS];
#pragma unroll
  for (int s = 0; s < DS; ++s) {
    A[s] = -__expf(A_log[d * DS + s]);
    h[s] = 0.f; P[s] = 1.f;
  }
  size_t bl0 = (size_t)b * SL + c * CL;
  size_t base = bl0 * DI + d;
  size_t xb = bl0 * DXP + DR;
  for (int l = 0; l < CL; ++l) {
    float dtv = to_f(dts[base]);
    float uv = to_f(u[base]);
    float du = dtv * uv;
#pragma unroll
    for (int s = 0; s < DS; ++s) {
      float Bv = xdbl[xb + s];
      float dA = __expf(dtv * A[s]);
      h[s] = dA * h[s] + du * Bv;
      P[s] *= dA;
    }
    base += DI;
    xb += DXP;
  }
  size_t o = ((size_t)(b * NC + c) * DS) * DI + d;
#pragma unroll
  for (int s = 0; s < DS; ++s) {
    Pbuf[o + (size_t)s * DI] = P[s];
    Qbuf[o + (size_t)s * DI] = h[s];
  }
}

__global__ __launch_bounds__(256) void scan_p2(float* __restrict__ Pbuf,
                                               float* __restrict__ Qbuf) {
  int bid = blockIdx.x;
  int b = bid >> 7;
  int s = (bid >> 3) & (DS - 1);
  int d = (bid & 7) * 256 + threadIdx.x;
  float h = 0.f;
  for (int c = 0; c < NC; ++c) {
    size_t idx = ((size_t)((b * NC + c) * DS + s)) * DI + d;
    float Pv = Pbuf[idx];
    float qv = Qbuf[idx];
    Qbuf[idx] = h;
    h = Pv * h + qv;
  }
}

__global__ __launch_bounds__(256) void scan_p3(const bf16* __restrict__ dts,
                                               bf16* __restrict__ u,
                                               const float* __restrict__ xdbl,
                                               const float* __restrict__ A_log,
                                               const float* __restrict__ Dp,
                                               const bf16* __restrict__ g,
                                               const float* __restrict__ Qbuf) {
  int bid = blockIdx.x;
  int b = bid >> 8;
  int c = (bid >> 3) & (NC - 1);
  int d = (bid & 7) * 256 + threadIdx.x;

  float A[DS], h[DS];
  size_t o = ((size_t)(b * NC + c) * DS) * DI + d;
#pragma unroll
  for (int s = 0; s < DS; ++s) {
    A[s] = -__expf(A_log[d * DS + s]);
    h[s] = Qbuf[o + (size_t)s * DI];
  }
  float Dd = Dp[d];
  size_t bl0 = (size_t)b * SL + c * CL;
  size_t base = bl0 * DI + d;
  size_t xb = bl0 * DXP + DR;
  for (int l = 0; l < CL; ++l) {
    float dtv = to_f(dts[base]);
    float uv = to_f(u[base]);
    float gv = to_f(g[base]);
    float du = dtv * uv;
    float p0 = 0.f, p1 = 0.f, p2 = 0.f, p3 = 0.f;
#pragma unroll
    for (int s = 0; s < DS; s += 4) {
      float dA0 = __expf(dtv * A[s + 0]);
      float dA1 = __expf(dtv * A[s + 1]);
      float dA2 = __expf(dtv * A[s + 2]);
      float dA3 = __expf(dtv * A[s + 3]);
      h[s + 0] = dA0 * h[s + 0] + du * xdbl[xb + s + 0];
      h[s + 1] = dA1 * h[s + 1] + du * xdbl[xb + s + 1];
      h[s + 2] = dA2 * h[s + 2] + du * xdbl[xb + s + 2];
      h[s + 3] = dA3 * h[s + 3] + du * xdbl[xb + s + 3];
      p0 += h[s + 0] * xdbl[xb + DS + s + 0];
      p1 += h[s + 1] * xdbl[xb + DS + s + 1];
      p2 += h[s + 2] * xdbl[xb + DS + s + 2];
      p3 += h[s + 3] * xdbl[xb + DS + s + 3];
    }
    float yv = ((p0 + p1) + (p2 + p3)) + Dd * uv;
    u[base] = from_f<bf16>(yv * gv);
    base += DI;
    xb += DXP;
  }
}

extern "C" void kernel_launch(void* const* d_in, const int* in_sizes, int n_in,
                              void* d_out, int out_size, void* d_ws, size_t ws_size,
                              hipStream_t stream) {
  const float* x        = (const float*)d_in[0];
  const float* norm_w   = (const float*)d_in[1];
  const float* in_projw = (const float*)d_in[2];
  const float* conv_w   = (const float*)d_in[3];
  const float* conv_b   = (const float*)d_in[4];
  const float* x_projw  = (const float*)d_in[5];
  const float* dt_projw = (const float*)d_in[6];
  const float* dt_projb = (const float*)d_in[7];
  const float* A_log    = (const float*)d_in[8];
  const float* Dp       = (const float*)d_in[9];
  const float* out_projw= (const float*)d_in[10];
  float* out = (float*)d_out;

  // ---- workspace (~104 MiB), lifetime overlays ----
  char* wsb = (char*)d_ws;
  bf16* x_buf  = (bf16*)wsb;                           // x half; later dt; later opw_bf
  bf16* z_buf  = (bf16*)(wsb + (size_t)BL * DI * 2);   // silu(z) gate
  bf16* u_buf  = (bf16*)(wsb + (size_t)BL * DI * 4);   // xnorm_bf (early) then u/y
  char* ovl    = wsb + (size_t)BL * DI * 6;            // 8 MiB overlay
  bf16* ipw_bf = (bf16*)ovl;                           // phase A: in_proj w bf16 (8 MiB)
  // phase B overlay (after in_proj):
  float* xdbl   = (float*)ovl;                                 // 3 MiB
  bf16*  xpw_bf = (bf16*)(ovl + 3145728);                      // 0.375 MiB
  bf16*  dtw_bf = (bf16*)(ovl + 3538944);                      // 0.25 MiB
  bf16*  dtin_bf= (bf16*)(ovl + 3801088);                      // 1 MiB
  bf16* xnorm_bf = u_buf;
  bf16* dt_buf   = x_buf;   // x half dead after conv
  bf16* opw_bf   = x_buf;   // dt dead after scan p3
  float* Ppart = out;       // d_out scratch: xproj partials (24 MiB), dead after xred
  float* Pbuf = out;        // d_out scratch until out_proj
  float* Qbuf = out + (size_t)NB * NC * DS * DI;

  // 1. in_proj weights -> bf16
  f2b_k<<<(2 * DI * DM) / 256, 256, 0, stream>>>(in_projw, ipw_bf, 2 * DI * DM);
  // 2. RMSNorm -> bf16
  rmsnorm_k<<<BL, 256, 0, stream>>>(x, norm_w, xnorm_bf);
  // 3. in_proj (256x256 8-phase MFMA): x half -> x_buf ; z half silu -> z_buf
  gemm256<1><<<(BL / 256) * (2 * DI / 256), 512, 0, stream>>>(
      xnorm_bf, ipw_bf, BL, 2 * DI, DM, x_buf, z_buf, DI, nullptr, nullptr);
  // 4. causal conv + silu -> u_buf (time-strip, register sliding window)
  conv_silu_k<<<NB * (SL / TSTRIP), 256, 0, stream>>>(x_buf, conv_w, conv_b, u_buf);
  // 5. x_proj: convert weights, split-K MFMA into partial buffers, reduce (+dtex fused)
  f2b_k<<<(DXP * DI + 255) / 256, 256, 0, stream>>>(x_projw, xpw_bf, DXP * DI);
  f2b_k<<<(DI * DR) / 256, 256, 0, stream>>>(dt_projw, dtw_bf, DI * DR);
  xproj_k<<<dim3(XNS, BL / 128), 256, 0, stream>>>(u_buf, xpw_bf, Ppart);
  xred_k<<<(BL * DXP) / 256, 256, 0, stream>>>(Ppart, xdbl, dtin_bf);
  // 6. dt_proj (MFMA, fused bias+softplus) -> dt_buf
  gemm_mfma<3><<<dim3(DI / TN, BL / TM), 256, 0, stream>>>(
      dtin_bf, dtw_bf, BL, DI, DR, dt_buf, nullptr, 0, nullptr, nullptr, dt_projb);
  // 7. chunked scan
  scan_p1<<<NB * NC * (DI / 256), 256, 0, stream>>>(dt_buf, u_buf, xdbl, A_log, Pbuf, Qbuf);
  scan_p2<<<NB * DS * (DI / 256), 256, 0, stream>>>(Pbuf, Qbuf);
  scan_p3<<<NB * NC * (DI / 256), 256, 0, stream>>>(dt_buf, u_buf, xdbl, A_log, Dp, z_buf, Qbuf);
  // 8. out_proj weights -> bf16, out_proj (256x128 pipelined, full grid) + residual
  f2b_k<<<(DM * DI) / 256, 256, 0, stream>>>(out_projw, opw_bf, DM * DI);
  gemm_np<2><<<(BL / 256) * (DM / 128), 512, 0, stream>>>(
      u_buf, opw_bf, BL, DM, DI, nullptr, nullptr, 0, out, x);
}

// Round 7
// 431.750 us; speedup vs baseline: 1.1657x; 1.0109x over previous
//
#include <hip/hip_runtime.h>
#include <hip/hip_bf16.h>
#include <math.h>

#define DM 1024   // d_model
#define DI 2048   // d_inner
#define DS 16     // d_state
#define DC 4      // d_conv
#define DR 64     // dt_rank
#define NB 4      // batch
#define SL 2048   // seqlen
#define BL (NB * SL)        // 8192 rows
#define DXP (DR + 2 * DS)   // 96
#define NC 32               // scan chunks
#define CL (SL / NC)        // 64 steps per chunk
#define XNS 8               // x_proj K-splits (partial buffers, no atomics)

typedef __hip_bfloat16 bf16;
typedef __attribute__((ext_vector_type(8))) short short8;
typedef __attribute__((ext_vector_type(4))) float floatx4;
typedef unsigned int u32;

__device__ __forceinline__ float to_f(float v) { return v; }
__device__ __forceinline__ float to_f(bf16 v) { return __bfloat162float(v); }
template <typename T> __device__ __forceinline__ T from_f(float v);
template <> __device__ __forceinline__ float from_f<float>(float v) { return v; }
template <> __device__ __forceinline__ bf16 from_f<bf16>(float v) { return __float2bfloat16(v); }

__device__ __forceinline__ float bfbits2f(unsigned short u) {
  u32 b = ((u32)u) << 16;
  return __builtin_bit_cast(float, b);
}
__device__ __forceinline__ ushort f2bfbits(float v) {
  bf16 b = __float2bfloat16(v);
  return (ushort)__builtin_bit_cast(short, b);
}
// fast silu: x * rcp(1+e^-x)  (v_rcp_f32, ~1 ulp — fine for bf16 outputs)
__device__ __forceinline__ float fsilu(float v) {
  return v * __builtin_amdgcn_rcpf(1.f + __expf(-v));
}

// async global->LDS, 16B per lane. LDS dest = wave-uniform base + lane*16.
__device__ __forceinline__ void gload16(const ushort* g, ushort* l) {
  __builtin_amdgcn_global_load_lds((const __attribute__((address_space(1))) void*)g,
                                   (__attribute__((address_space(3))) void*)l,
                                   16, 0, 0);
}

__device__ __forceinline__ void vmw4() { asm volatile("s_waitcnt vmcnt(4)" ::: "memory"); }
__device__ __forceinline__ void vmw2() { asm volatile("s_waitcnt vmcnt(2)" ::: "memory"); }
__device__ __forceinline__ void vmw0() { asm volatile("s_waitcnt vmcnt(0)" ::: "memory"); }
// raw barrier (NO implicit vmcnt drain) with compiler-only memory fences so
// LDS reads/stages can't migrate across phases.
__device__ __forceinline__ void barx() {
  asm volatile("" ::: "memory");
  __builtin_amdgcn_s_barrier();
  asm volatile("" ::: "memory");
}

// ---------------- fp32 -> bf16 conversion ----------------
__global__ __launch_bounds__(256) void f2b_k(const float* __restrict__ src,
                                             bf16* __restrict__ dst, int n) {
  int i = blockIdx.x * 256 + threadIdx.x;
  if (i < n) dst[i] = from_f<bf16>(src[i]);
}

// ---------------- RMSNorm (bf16 out, float4 one-pass) ----------------
__global__ __launch_bounds__(256) void rmsnorm_k(const float* __restrict__ x,
                                                 const float* __restrict__ w,
                                                 bf16* __restrict__ o) {
  int row = blockIdx.x;
  const float4* xr = (const float4*)(x + (size_t)row * DM);
  float4 v = xr[threadIdx.x];          // DM = 1024 = 256 threads * 4
  float ss = v.x * v.x + v.y * v.y + v.z * v.z + v.w * v.w;
  for (int off = 32; off > 0; off >>= 1) ss += __shfl_down(ss, off);
  __shared__ float sred[4];
  __shared__ float sscale;
  if ((threadIdx.x & 63) == 0) sred[threadIdx.x >> 6] = ss;
  __syncthreads();
  if (threadIdx.x == 0) {
    float t = sred[0] + sred[1] + sred[2] + sred[3];
    sscale = rsqrtf(t / (float)DM + 1.1920929e-7f);
  }
  __syncthreads();
  float sc = sscale;
  float4 wv = ((const float4*)w)[threadIdx.x];
  ushort4 pk;
  pk.x = f2bfbits(v.x * sc * wv.x);
  pk.y = f2bfbits(v.y * sc * wv.y);
  pk.z = f2bfbits(v.z * sc * wv.z);
  pk.w = f2bfbits(v.w * sc * wv.w);
  ((ushort4*)((ushort*)o + (size_t)row * DM))[threadIdx.x] = pk;
}

// ======== 256x256 8-phase pipelined MFMA GEMM (in_proj) ========
// st_16x32 LDS swizzle (T2), half-tile prefetch + counted vmcnt (T3+T4),
// setprio (T5), N-fastest XCD swizzle.  R7: OPERAND-SWAPPED MFMA —
// mfma(b,a) puts 4 consecutive OUTPUT COLUMNS in each lane's regs, so the
// epilogue stores ushort4 (8B/lane, coalesced) instead of 4x scalar bf16
// (2B sub-line writes that showed up as ~50MB of C write-allocate FETCH).
template <int MODE>
__global__ __launch_bounds__(512, 1) void gemm256(const bf16* __restrict__ A,
                                                  const bf16* __restrict__ W,
                                                  int M, int N, int K,
                                                  bf16* __restrict__ Cx,
                                                  bf16* __restrict__ Cz, int nsplit,
                                                  float* __restrict__ Cf,
                                                  const float* __restrict__ R) {
  __shared__ ushort SH[65536];   // 128 KiB: A @ 0..64K, B @ 64K..128K (bytes)
  const int tid = threadIdx.x;
  const int lane = tid & 63, wv = tid >> 6;
  const int wr = wv >> 2, wc = wv & 3;
  const int row15 = lane & 15, quad = lane >> 4;

  // XCD-aware block swizzle, N-fastest within each XCD chunk
  int ntm = M >> 8, ntn = N >> 8, nwg = ntm * ntn;
  int bid = blockIdx.x;
  int swz = (bid & 7) * (nwg >> 3) + (bid >> 3);
  int bm0 = (swz / ntn) << 8, bn0 = (swz % ntn) << 8;

  const int nt = K >> 6;   // K-tiles
  const ushort* Au = (const ushort*)A;
  const ushort* Wu = (const ushort*)W;

  // staging: lane's inverse-swizzled source chunk (involution in chunk space)
  const int w4u = lane ^ (((lane >> 5) & 1) << 1);
  // fragment-read swizzled byte offset within a 1024B subtile
  const int Wsw = (((row15 << 6) | (quad << 4)) ^ (((row15 >> 3) & 1) << 5));
  const char* SHb = (const char*)SH;
  // ds_read base byte offsets (cur encoded in the two variants)
  const int Abase0 = (wr << 14) + Wsw;
  const int Abase1 = 32768 + (wr << 14) + Wsw;
  const int Bbase0 = 65536 + ((wc >> 1) << 14) + ((wc & 1) << 13) + Wsw;
  const int Bbase1 = Bbase0 + 32768;

  auto stageA = [&](int tt, int half, int buf) {
    const ushort* g = Au + (size_t)(bm0 + half * 128) * K + tt * 64;
    char* lds = (char*)SH + (size_t)(buf * 2 + half) * 16384;
#pragma unroll
    for (int i = 0; i < 2; ++i) {
      int sub = wv + i * 8;
      int r = ((sub >> 1) << 4) | (w4u >> 2);
      int ce = ((sub & 1) << 5) | ((w4u & 3) << 3);
      gload16(g + (size_t)r * K + ce, (ushort*)(lds + sub * 1024));
    }
  };
  auto stageB = [&](int tt, int half, int buf) {
    const ushort* g = Wu + (size_t)(bn0 + half * 128) * K + tt * 64;
    char* lds = (char*)SH + 65536 + (size_t)(buf * 2 + half) * 16384;
#pragma unroll
    for (int i = 0; i < 2; ++i) {
      int sub = wv + i * 8;
      int r = ((sub >> 1) << 4) | (w4u >> 2);
      int ce = ((sub & 1) << 5) | ((w4u & 3) << 3);
      gload16(g + (size_t)r * K + ce, (ushort*)(lds + sub * 1024));
    }
  };

  short8 a_f[4][2], bq[2][2][2];   // bq[nh][ni][kk]; bq[0] retained q0->q3
  floatx4 acc[8][4] = {};

#define LDA_(base, mh) do { _Pragma("unroll") for (int mi = 0; mi < 4; ++mi) \
  { _Pragma("unroll") for (int kk = 0; kk < 2; ++kk) \
    a_f[mi][kk] = *(const short8*)(SHb + (base) + ((((mh)*4 + mi)*2 + kk) << 10)); } } while (0)
#define LDB_(base, nh) do { _Pragma("unroll") for (int ni = 0; ni < 2; ++ni) \
  { _Pragma("unroll") for (int kk = 0; kk < 2; ++kk) \
    bq[nh][ni][kk] = *(const short8*)(SHb + (base) + (((((nh)*2 + ni)*2 + kk)) << 10)); } } while (0)
// operand-swapped: lane&15 -> output ROW, quad*4+reg -> output COL
#define MM_(mh, nh) do { __builtin_amdgcn_s_setprio(1); \
  _Pragma("unroll") for (int mi = 0; mi < 4; ++mi) \
  { _Pragma("unroll") for (int ni = 0; ni < 2; ++ni) \
    { _Pragma("unroll") for (int kk = 0; kk < 2; ++kk) \
      acc[(mh)*4+mi][(nh)*2+ni] = __builtin_amdgcn_mfma_f32_16x16x32_bf16( \
          bq[nh][ni][kk], a_f[mi][kk], acc[(mh)*4+mi][(nh)*2+ni], 0, 0, 0); } } \
  __builtin_amdgcn_s_setprio(0); } while (0)

#define TILE_(t, AB, BB, curbuf, nxtbuf) do { \
  int tp1 = (t) + 1, tp2 = (t) + 2; \
  LDA_(AB, 0); LDB_(BB, 0); \
  if (tp1 < nt) stageA(tp1, 0, nxtbuf); \
  barx(); MM_(0, 0); barx(); \
  LDB_(BB, 1); \
  if (tp1 < nt) stageA(tp1, 1, nxtbuf); \
  barx(); MM_(0, 1); barx(); \
  LDA_(AB, 1); \
  if (tp2 < nt) stageB(tp2, 0, curbuf); \
  barx(); MM_(1, 1); barx(); \
  if (tp2 < nt) stageB(tp2, 1, curbuf); \
  barx(); MM_(1, 0); \
  if (tp2 < nt) vmw4(); else vmw0(); \
  barx(); \
} while (0)

  // prologue: tile0's 4 halves + tile1's B halves (6 halves = 12 loads)
  stageB(0, 0, 0); stageB(0, 1, 0); stageA(0, 0, 0); stageA(0, 1, 0);
  stageB(1, 0, 1); stageB(1, 1, 1);
  vmw4();   // tile0 complete; tile1's B halves (4 loads) in flight
  barx();

  for (int t = 0; t < nt; t += 2) {
    TILE_(t, Abase0, Bbase0, 0, 1);
    TILE_(t + 1, Abase1, Bbase1, 1, 0);
  }
#undef TILE_
#undef MM_
#undef LDB_
#undef LDA_

  // epilogue (swapped layout): lane owns row (.. + row15), cols (.. + quad*4 + 0..3)
#pragma unroll
  for (int mi8 = 0; mi8 < 8; ++mi8) {
    int grow = bm0 + wr * 128 + mi8 * 16 + row15;
#pragma unroll
    for (int ni4 = 0; ni4 < 4; ++ni4) {
      int gc = bn0 + wc * 64 + ni4 * 16 + quad * 4;
      floatx4 v = acc[mi8][ni4];
      if (MODE == 1) {
        if (gc < nsplit) {
          ushort4 pk = {f2bfbits(v[0]), f2bfbits(v[1]), f2bfbits(v[2]), f2bfbits(v[3])};
          *(ushort4*)((ushort*)Cx + (size_t)grow * DI + gc) = pk;
        } else {
          ushort4 pk = {f2bfbits(fsilu(v[0])), f2bfbits(fsilu(v[1])),
                        f2bfbits(fsilu(v[2])), f2bfbits(fsilu(v[3]))};
          *(ushort4*)((ushort*)Cz + (size_t)grow * DI + (gc - nsplit)) = pk;
        }
      } else {
        size_t o = (size_t)grow * N + gc;
        float4 r4 = *(const float4*)&R[o];
        float4 o4 = {v[0] + r4.x, v[1] + r4.y, v[2] + r4.z, v[3] + r4.w};
        *(float4*)&Cf[o] = o4;
      }
    }
  }
}

// ======== 256x128 pipelined MFMA GEMM (out_proj; full grid at N=1024) ====
// 8 waves (4M x 2N), fragment pre-read pipeline; LDS 96 KiB; N-fastest XCD
// swizzle.  R7: operand-swapped MFMA -> float4 C stores + float4 R loads.
template <int MODE>
__global__ __launch_bounds__(512, 1) void gemm_np(const bf16* __restrict__ A,
                                                  const bf16* __restrict__ W,
                                                  int M, int N, int K,
                                                  bf16* __restrict__ Cx,
                                                  bf16* __restrict__ Cz, int nsplit,
                                                  float* __restrict__ Cf,
                                                  const float* __restrict__ R) {
  __shared__ ushort SH[49152];   // 96 KiB
  const int tid = threadIdx.x;
  const int lane = tid & 63, wv = tid >> 6;
  const int wr = wv >> 1, wc = wv & 1;          // 4M x 2N wave grid
  const int row15 = lane & 15, quad = lane >> 4;

  // XCD-aware block swizzle, N-fastest within each XCD chunk
  int ntm = M >> 8, ntn = N >> 7, nwg = ntm * ntn;
  int bid = blockIdx.x;
  int swz = (bid & 7) * (nwg >> 3) + (bid >> 3);
  int bm0 = (swz / ntn) << 8, bn0 = (swz % ntn) << 7;

  const int nt = K >> 6;   // K-tiles (even)
  const ushort* Au = (const ushort*)A;
  const ushort* Wu = (const ushort*)W;
  const ushort* Ag = Au + (u32)bm0 * (u32)K;
  const ushort* Bg = Wu + (u32)bn0 * (u32)K;

  // staging coords: lane's inverse-swizzled chunk (st_16x32 involution)
  const int w4u = lane ^ (((lane >> 5) & 1) << 1);
  const int sub0 = wv, sub1 = wv + 8;
  const int r0 = ((sub0 >> 1) << 4) | (w4u >> 2);
  const int c0 = ((sub0 & 1) << 5) | ((w4u & 3) << 3);
  const int r1 = ((sub1 >> 1) << 4) | (w4u >> 2);
  const int c1 = ((sub1 & 1) << 5) | ((w4u & 3) << 3);
  ushort* shA = (ushort*)SH;            // 2 bufs x 16384 ushorts
  ushort* shB = (ushort*)SH + 32768;    // 2 bufs x 8192 ushorts

  auto stage = [&](const ushort* gbase, int rowoff, int tt, ushort* lbase) {
    gload16(gbase + (u32)(rowoff + r0) * (u32)K + (u32)(tt * 64 + c0), lbase + (sub0 << 9));
    gload16(gbase + (u32)(rowoff + r1) * (u32)K + (u32)(tt * 64 + c1), lbase + (sub1 << 9));
  };

  // fragment-read swizzled byte offset within a 1024B subtile
  const int Wsw = (((row15 << 6) | (quad << 4)) ^ (((row15 >> 3) & 1) << 5));
  const char* SHb = (const char*)SH;
  const int AB0 = (wr << 13) + Wsw;
  const int AB1 = 32768 + AB0;
  const int BB0 = 65536 + (wc << 13) + Wsw;
  const int BB1 = BB0 + 16384;

  short8 a0[2][2], a1[2][2], bq0A[2][2], bq0B[2][2], bq1[2][2];
  floatx4 acc[4][4] = {};

#define LDA_(dst, base, mh) do { _Pragma("unroll") for (int i_ = 0; i_ < 2; ++i_) \
  { _Pragma("unroll") for (int kk = 0; kk < 2; ++kk) \
    dst[i_][kk] = *(const short8*)(SHb + (base) + ((((mh)*2 + i_)*2 + kk) << 10)); } } while (0)
#define LDB_(dst, base, nh) do { _Pragma("unroll") for (int j_ = 0; j_ < 2; ++j_) \
  { _Pragma("unroll") for (int kk = 0; kk < 2; ++kk) \
    dst[j_][kk] = *(const short8*)(SHb + (base) + ((((nh)*2 + j_)*2 + kk) << 10)); } } while (0)
// operand-swapped
#define MM_(aset, bset, mh, nh) do { __builtin_amdgcn_s_setprio(1); \
  _Pragma("unroll") for (int i_ = 0; i_ < 2; ++i_) \
  { _Pragma("unroll") for (int j_ = 0; j_ < 2; ++j_) \
    { _Pragma("unroll") for (int kk = 0; kk < 2; ++kk) \
      acc[(mh)*2+i_][(nh)*2+j_] = __builtin_amdgcn_mfma_f32_16x16x32_bf16( \
          bset[j_][kk], aset[i_][kk], acc[(mh)*2+i_][(nh)*2+j_], 0, 0, 0); } } \
  __builtin_amdgcn_s_setprio(0); } while (0)

#define TILE_(t, ABc, BBc, ABn, BBn, BQU, BQF, CURB, NXTB) do { \
  int tp1 = (t) + 1, tp2 = (t) + 2; \
  /* q0 */ \
  LDB_(bq1, BBc, 1); \
  if (tp1 < nt) stage(Ag, 0, tp1, shA + (NXTB) * 16384); \
  barx(); MM_(a0, BQU, 0, 0); barx(); \
  /* q1 */ \
  LDA_(a1, ABc, 1); \
  if (tp1 < nt) stage(Ag, 128, tp1, shA + (NXTB) * 16384 + 8192); \
  barx(); MM_(a0, bq1, 0, 1); barx(); \
  /* q2 */ \
  if (tp2 < nt) stage(Bg, 0, tp2, shB + (CURB) * 8192); \
  barx(); MM_(a1, bq1, 1, 1); \
  if (tp2 < nt) vmw2(); else vmw0(); \
  barx(); \
  /* q3 */ \
  if (tp1 < nt) { LDA_(a0, ABn, 0); LDB_(BQF, BBn, 0); } \
  barx(); MM_(a1, BQU, 1, 0); barx(); \
} while (0)

  // prologue: B(0), A(0)-lo, A(0)-hi -> buf0 ; B(1) -> buf1
  stage(Bg, 0, 0, shB);
  stage(Ag, 0, 0, shA);
  stage(Ag, 128, 0, shA + 8192);
  if (nt > 1) { stage(Bg, 0, 1, shB + 8192); vmw2(); } else { vmw0(); }
  barx();
  LDA_(a0, AB0, 0);
  LDB_(bq0A, BB0, 0);

  for (int t = 0; t < nt; t += 2) {
    TILE_(t,     AB0, BB0, AB1, BB1, bq0A, bq0B, 0, 1);
    TILE_(t + 1, AB1, BB1, AB0, BB0, bq0B, bq0A, 1, 0);
  }
#undef TILE_
#undef MM_
#undef LDB_
#undef LDA_

  // epilogue (swapped layout)
#pragma unroll
  for (int mi = 0; mi < 4; ++mi) {
    int grow = bm0 + wr * 64 + mi * 16 + row15;
#pragma unroll
    for (int ni = 0; ni < 4; ++ni) {
      int gc = bn0 + wc * 64 + ni * 16 + quad * 4;
      floatx4 v = acc[mi][ni];
      if (MODE == 1) {
        if (gc < nsplit) {
          ushort4 pk = {f2bfbits(v[0]), f2bfbits(v[1]), f2bfbits(v[2]), f2bfbits(v[3])};
          *(ushort4*)((ushort*)Cx + (size_t)grow * DI + gc) = pk;
        } else {
          ushort4 pk = {f2bfbits(fsilu(v[0])), f2bfbits(fsilu(v[1])),
                        f2bfbits(fsilu(v[2])), f2bfbits(fsilu(v[3]))};
          *(ushort4*)((ushort*)Cz + (size_t)grow * DI + (gc - nsplit)) = pk;
        }
      } else {
        size_t o = (size_t)grow * N + gc;
        float4 r4 = *(const float4*)&R[o];
        float4 o4 = {v[0] + r4.x, v[1] + r4.y, v[2] + r4.z, v[3] + r4.w};
        *(float4*)&Cf[o] = o4;
      }
    }
  }
}

// ======== 128x128 MFMA GEMM (dt_proj, K=64) — operand-swapped epilogue ========
#define TM 128
#define TN 128
#define TK 32
#define LDK 40
template <int MODE>
__global__ __launch_bounds__(256) void gemm_mfma(const bf16* __restrict__ A,
                                                 const bf16* __restrict__ W,
                                                 int M, int N, int K,
                                                 bf16* __restrict__ Cx,
                                                 bf16* __restrict__ Cz, int nsplit,
                                                 float* __restrict__ Cf,
                                                 const float* __restrict__ R,
                                                 const float* __restrict__ bias) {
  __shared__ ushort Asm[TM][TK];   // linear — required by global_load_lds
  __shared__ ushort Bsm[TN][TK];
  int bm = blockIdx.y * TM, bn = blockIdx.x * TN;
  int tid = threadIdx.x;
  int lane = tid & 63, wave = tid >> 6;
  int wm = (wave & 1) * 64, wn = (wave >> 1) * 64;
  int row15 = lane & 15, quad = lane >> 4;

  int srow = lane >> 2;          // 0..15
  int scol = (lane & 3) * 8;     // 0,8,16,24
  int s0 = wave * 2, s1 = wave * 2 + 1;

  const ushort* Au = (const ushort*)A;
  const ushort* Wu = (const ushort*)W;
  const ushort* ag0 = Au + (size_t)(bm + s0 * 16 + srow) * K + scol;
  const ushort* ag1 = Au + (size_t)(bm + s1 * 16 + srow) * K + scol;
  const ushort* bg0 = Wu + (size_t)(bn + s0 * 16 + srow) * K + scol;
  const ushort* bg1 = Wu + (size_t)(bn + s1 * 16 + srow) * K + scol;
  ushort* la0 = &Asm[s0 * 16][0];
  ushort* la1 = &Asm[s1 * 16][0];
  ushort* lb0 = &Bsm[s0 * 16][0];
  ushort* lb1 = &Bsm[s1 * 16][0];

  floatx4 acc[4][4] = {};

  for (int k0 = 0; k0 < K; k0 += TK) {
    gload16(ag0 + k0, la0);
    gload16(ag1 + k0, la1);
    gload16(bg0 + k0, lb0);
    gload16(bg1 + k0, lb1);
    __syncthreads();
    short8 a_f[4], b_f[4];
#pragma unroll
    for (int i = 0; i < 4; ++i)
      a_f[i] = *(const short8*)&Asm[wm + i * 16 + row15][quad * 8];
#pragma unroll
    for (int j = 0; j < 4; ++j)
      b_f[j] = *(const short8*)&Bsm[wn + j * 16 + row15][quad * 8];
#pragma unroll
    for (int i = 0; i < 4; ++i)
#pragma unroll
      for (int j = 0; j < 4; ++j)
        acc[i][j] = __builtin_amdgcn_mfma_f32_16x16x32_bf16(b_f[j], a_f[i], acc[i][j], 0, 0, 0);
    __syncthreads();
  }
  // swapped epilogue: lane owns row (..+row15), cols (..+quad*4+0..3)
#pragma unroll
  for (int mi = 0; mi < 4; ++mi) {
    int grow = bm + wm + mi * 16 + row15;
#pragma unroll
    for (int ni = 0; ni < 4; ++ni) {
      int gc = bn + wn + ni * 16 + quad * 4;
      floatx4 v = acc[mi][ni];
      if (MODE == 1) {
        if (gc < nsplit) {
          ushort4 pk = {f2bfbits(v[0]), f2bfbits(v[1]), f2bfbits(v[2]), f2bfbits(v[3])};
          *(ushort4*)((ushort*)Cx + (size_t)grow * DI + gc) = pk;
        } else {
          ushort4 pk = {f2bfbits(fsilu(v[0])), f2bfbits(fsilu(v[1])),
                        f2bfbits(fsilu(v[2])), f2bfbits(fsilu(v[3]))};
          *(ushort4*)((ushort*)Cz + (size_t)grow * DI + (gc - nsplit)) = pk;
        }
      } else if (MODE == 2) {
        size_t o = (size_t)grow * N + gc;
        float4 r4 = *(const float4*)&R[o];
        float4 o4 = {v[0] + r4.x, v[1] + r4.y, v[2] + r4.z, v[3] + r4.w};
        *(float4*)&Cf[o] = o4;
      } else {  // MODE 3: dt softplus, packed
        float4 b4 = *(const float4*)&bias[gc];
        float t0 = v[0] + b4.x, t1 = v[1] + b4.y, t2 = v[2] + b4.z, t3 = v[3] + b4.w;
        float s0_ = (t0 > 20.f) ? t0 : __logf(1.f + __expf(t0));
        float s1_ = (t1 > 20.f) ? t1 : __logf(1.f + __expf(t1));
        float s2_ = (t2 > 20.f) ? t2 : __logf(1.f + __expf(t2));
        float s3_ = (t3 > 20.f) ? t3 : __logf(1.f + __expf(t3));
        ushort4 pk = {f2bfbits(s0_), f2bfbits(s1_), f2bfbits(s2_), f2bfbits(s3_)};
        *(ushort4*)((ushort*)Cx + (size_t)grow * N + gc) = pk;
      }
    }
  }
}

// ======== x_proj split-K MFMA, partial buffers (no atomics, swapped epilogue) ====
__global__ __launch_bounds__(256) void xproj_k(const bf16* __restrict__ u,
                                               const bf16* __restrict__ w,
                                               float* __restrict__ Ppart) {
  __shared__ ushort Asm[128][LDK];
  __shared__ ushort Bsm[96][LDK];
  int kbase = blockIdx.x * (DI / XNS);
  int bm = blockIdx.y * 128;
  int tid = threadIdx.x;
  int lane = tid & 63, wave = tid >> 6;
  int row15 = lane & 15, quad = lane >> 4;
  int srow = tid >> 1, skoff = (tid & 1) * 16;

  floatx4 acc[2][6] = {};
  const ushort* Au = (const ushort*)u;
  const ushort* Wu = (const ushort*)w;
  for (int k0 = kbase; k0 < kbase + (DI / XNS); k0 += TK) {
    const ushort* ag = Au + (size_t)(bm + srow) * DI + k0 + skoff;
    *(short8*)&Asm[srow][skoff]     = *(const short8*)ag;
    *(short8*)&Asm[srow][skoff + 8] = *(const short8*)(ag + 8);
    if (tid < 192) {
      const ushort* wg = Wu + (size_t)srow * DI + k0 + skoff;
      *(short8*)&Bsm[srow][skoff]     = *(const short8*)wg;
      *(short8*)&Bsm[srow][skoff + 8] = *(const short8*)(wg + 8);
    }
    __syncthreads();
    short8 a_f[2], b_f[6];
#pragma unroll
    for (int i = 0; i < 2; ++i)
      a_f[i] = *(const short8*)&Asm[wave * 32 + i * 16 + row15][quad * 8];
#pragma unroll
    for (int j = 0; j < 6; ++j)
      b_f[j] = *(const short8*)&Bsm[j * 16 + row15][quad * 8];
#pragma unroll
    for (int i = 0; i < 2; ++i)
#pragma unroll
      for (int j = 0; j < 6; ++j)
        acc[i][j] = __builtin_amdgcn_mfma_f32_16x16x32_bf16(b_f[j], a_f[i], acc[i][j], 0, 0, 0);
    __syncthreads();
  }
  float* P = Ppart + (size_t)blockIdx.x * ((size_t)BL * DXP);
#pragma unroll
  for (int mi = 0; mi < 2; ++mi) {
    int grow = bm + wave * 32 + mi * 16 + row15;
#pragma unroll
    for (int nj = 0; nj < 6; ++nj) {
      int gc = nj * 16 + quad * 4;
      floatx4 v = acc[mi][nj];
      float4 o4 = {v[0], v[1], v[2], v[3]};
      *(float4*)&P[(size_t)grow * DXP + gc] = o4;
    }
  }
}

// ---- reduce partials -> xdbl fp32; also emit dtin bf16 (fuses old dtex_k) ----
__global__ __launch_bounds__(256) void xred_k(const float* __restrict__ Ppart,
                                              float* __restrict__ xdbl,
                                              bf16* __restrict__ dtin) {
  int i = blockIdx.x * 256 + threadIdx.x;   // BL * DXP total
  float s = 0.f;
#pragma unroll
  for (int p = 0; p < XNS; ++p) s += Ppart[(size_t)p * ((size_t)BL * DXP) + i];
  xdbl[i] = s;
  int r = i / DXP, c = i - r * DXP;
  if (c < DR) dtin[r * DR + c] = from_f<bf16>(s);
}

// ---------------- causal depthwise conv (K=4) + SiLU ----------------
#define TSTRIP 8
__global__ __launch_bounds__(256) void conv_silu_k(const bf16* __restrict__ xin,
                                                   const float* __restrict__ cw,
                                                   const float* __restrict__ cb,
                                                   bf16* __restrict__ u) {
  int blk = blockIdx.x;                   // NB * (SL/TSTRIP) blocks
  int b = blk >> 8;
  int l0 = (blk & 255) * TSTRIP;
  int c0 = threadIdx.x * 8;

  float4 cw4[8];
  const float4* cwp = (const float4*)cw;
#pragma unroll
  for (int j = 0; j < 8; ++j) cw4[j] = cwp[c0 + j];
  float cbv[8];
  {
    float4 cb0 = *(const float4*)&cb[c0];
    float4 cb1 = *(const float4*)&cb[c0 + 4];
    cbv[0] = cb0.x; cbv[1] = cb0.y; cbv[2] = cb0.z; cbv[3] = cb0.w;
    cbv[4] = cb1.x; cbv[5] = cb1.y; cbv[6] = cb1.z; cbv[7] = cb1.w;
  }

  const ushort* base = (const ushort*)xin + ((size_t)(b * SL + l0) * DI + c0);
  ushort* ubase = (ushort*)u + ((size_t)(b * SL + l0) * DI + c0);

  short8 zz = {};
  short8 w0 = zz, w1 = zz, w2 = zz;
  if (l0 >= 3) {
    w0 = *(const short8*)(base - 3 * DI);
    w1 = *(const short8*)(base - 2 * DI);
    w2 = *(const short8*)(base - 1 * DI);
  }
#pragma unroll
  for (int l = 0; l < TSTRIP; ++l) {
    short8 w3 = *(const short8*)(base + (ptrdiff_t)l * DI);
    short8 outv;
#pragma unroll
    for (int j = 0; j < 8; ++j) {
      float a = cbv[j]
              + bfbits2f((unsigned short)w0[j]) * cw4[j].x
              + bfbits2f((unsigned short)w1[j]) * cw4[j].y
              + bfbits2f((unsigned short)w2[j]) * cw4[j].z
              + bfbits2f((unsigned short)w3[j]) * cw4[j].w;
      outv[j] = (short)f2bfbits(fsilu(a));
    }
    *(short8*)(ubase + (ptrdiff_t)l * DI) = outv;
    w0 = w1; w1 = w2; w2 = w3;
  }
}

// ======== chunked selective scan ========
__global__ __launch_bounds__(256) void scan_p1(const bf16* __restrict__ dts,
                                               const bf16* __restrict__ u,
                                               const float* __restrict__ xdbl,
                                               const float* __restrict__ A_log,
                                               float* __restrict__ Pbuf,
                                               float* __restrict__ Qbuf) {
  int bid = blockIdx.x;
  int b = bid >> 8;
  int c = (bid >> 3) & (NC - 1);
  int d = (bid & 7) * 256 + threadIdx.x;

  float A[DS], h[DS], P[DS];
#pragma unroll
  for (int s = 0; s < DS; ++s) {
    A[s] = -__expf(A_log[d * DS + s]);
    h[s] = 0.f; P[s] = 1.f;
  }
  size_t bl0 = (size_t)b * SL + c * CL;
  size_t base = bl0 * DI + d;
  size_t xb = bl0 * DXP + DR;
  for (int l = 0; l < CL; ++l) {
    float dtv = to_f(dts[base]);
    float uv = to_f(u[base]);
    float du = dtv * uv;
#pragma unroll
    for (int s = 0; s < DS; ++s) {
      float Bv = xdbl[xb + s];
      float dA = __expf(dtv * A[s]);
      h[s] = dA * h[s] + du * Bv;
      P[s] *= dA;
    }
    base += DI;
    xb += DXP;
  }
  size_t o = ((size_t)(b * NC + c) * DS) * DI + d;
#pragma unroll
  for (int s = 0; s < DS; ++s) {
    Pbuf[o + (size_t)s * DI] = P[s];
    Qbuf[o + (size_t)s * DI] = h[s];
  }
}

__global__ __launch_bounds__(256) void scan_p2(float* __restrict__ Pbuf,
                                               float* __restrict__ Qbuf) {
  int bid = blockIdx.x;
  int b = bid >> 7;
  int s = (bid >> 3) & (DS - 1);
  int d = (bid & 7) * 256 + threadIdx.x;
  float h = 0.f;
  for (int c = 0; c < NC; ++c) {
    size_t idx = ((size_t)((b * NC + c) * DS + s)) * DI + d;
    float Pv = Pbuf[idx];
    float qv = Qbuf[idx];
    Qbuf[idx] = h;
    h = Pv * h + qv;
  }
}

__global__ __launch_bounds__(256) void scan_p3(const bf16* __restrict__ dts,
                                               bf16* __restrict__ u,
                                               const float* __restrict__ xdbl,
                                               const float* __restrict__ A_log,
                                               const float* __restrict__ Dp,
                                               const bf16* __restrict__ g,
                                               const float* __restrict__ Qbuf) {
  int bid = blockIdx.x;
  int b = bid >> 8;
  int c = (bid >> 3) & (NC - 1);
  int d = (bid & 7) * 256 + threadIdx.x;

  float A[DS], h[DS];
  size_t o = ((size_t)(b * NC + c) * DS) * DI + d;
#pragma unroll
  for (int s = 0; s < DS; ++s) {
    A[s] = -__expf(A_log[d * DS + s]);
    h[s] = Qbuf[o + (size_t)s * DI];
  }
  float Dd = Dp[d];
  size_t bl0 = (size_t)b * SL + c * CL;
  size_t base = bl0 * DI + d;
  size_t xb = bl0 * DXP + DR;
  for (int l = 0; l < CL; ++l) {
    float dtv = to_f(dts[base]);
    float uv = to_f(u[base]);
    float gv = to_f(g[base]);
    float du = dtv * uv;
    float p0 = 0.f, p1 = 0.f, p2 = 0.f, p3 = 0.f;
#pragma unroll
    for (int s = 0; s < DS; s += 4) {
      float dA0 = __expf(dtv * A[s + 0]);
      float dA1 = __expf(dtv * A[s + 1]);
      float dA2 = __expf(dtv * A[s + 2]);
      float dA3 = __expf(dtv * A[s + 3]);
      h[s + 0] = dA0 * h[s + 0] + du * xdbl[xb + s + 0];
      h[s + 1] = dA1 * h[s + 1] + du * xdbl[xb + s + 1];
      h[s + 2] = dA2 * h[s + 2] + du * xdbl[xb + s + 2];
      h[s + 3] = dA3 * h[s + 3] + du * xdbl[xb + s + 3];
      p0 += h[s + 0] * xdbl[xb + DS + s + 0];
      p1 += h[s + 1] * xdbl[xb + DS + s + 1];
      p2 += h[s + 2] * xdbl[xb + DS + s + 2];
      p3 += h[s + 3] * xdbl[xb + DS + s + 3];
    }
    float yv = ((p0 + p1) + (p2 + p3)) + Dd * uv;
    u[base] = from_f<bf16>(yv * gv);
    base += DI;
    xb += DXP;
  }
}

extern "C" void kernel_launch(void* const* d_in, const int* in_sizes, int n_in,
                              void* d_out, int out_size, void* d_ws, size_t ws_size,
                              hipStream_t stream) {
  const float* x        = (const float*)d_in[0];
  const float* norm_w   = (const float*)d_in[1];
  const float* in_projw = (const float*)d_in[2];
  const float* conv_w   = (const float*)d_in[3];
  const float* conv_b   = (const float*)d_in[4];
  const float* x_projw  = (const float*)d_in[5];
  const float* dt_projw = (const float*)d_in[6];
  const float* dt_projb = (const float*)d_in[7];
  const float* A_log    = (const float*)d_in[8];
  const float* Dp       = (const float*)d_in[9];
  const float* out_projw= (const float*)d_in[10];
  float* out = (float*)d_out;

  // ---- workspace (~104 MiB), lifetime overlays ----
  char* wsb = (char*)d_ws;
  bf16* x_buf  = (bf16*)wsb;                           // x half; later dt; later opw_bf
  bf16* z_buf  = (bf16*)(wsb + (size_t)BL * DI * 2);   // silu(z) gate
  bf16* u_buf  = (bf16*)(wsb + (size_t)BL * DI * 4);   // xnorm_bf (early) then u/y
  char* ovl    = wsb + (size_t)BL * DI * 6;            // 8 MiB overlay
  bf16* ipw_bf = (bf16*)ovl;                           // phase A: in_proj w bf16 (8 MiB)
  // phase B overlay (after in_proj):
  float* xdbl   = (float*)ovl;                                 // 3 MiB
  bf16*  xpw_bf = (bf16*)(ovl + 3145728);                      // 0.375 MiB
  bf16*  dtw_bf = (bf16*)(ovl + 3538944);                      // 0.25 MiB
  bf16*  dtin_bf= (bf16*)(ovl + 3801088);                      // 1 MiB
  bf16* xnorm_bf = u_buf;
  bf16* dt_buf   = x_buf;   // x half dead after conv
  bf16* opw_bf   = x_buf;   // dt dead after scan p3
  float* Ppart = out;       // d_out scratch: xproj partials (24 MiB), dead after xred
  float* Pbuf = out;        // d_out scratch until out_proj
  float* Qbuf = out + (size_t)NB * NC * DS * DI;

  // 1. in_proj weights -> bf16
  f2b_k<<<(2 * DI * DM) / 256, 256, 0, stream>>>(in_projw, ipw_bf, 2 * DI * DM);
  // 2. RMSNorm -> bf16
  rmsnorm_k<<<BL, 256, 0, stream>>>(x, norm_w, xnorm_bf);
  // 3. in_proj (256x256 8-phase MFMA): x half -> x_buf ; z half silu -> z_buf
  gemm256<1><<<(BL / 256) * (2 * DI / 256), 512, 0, stream>>>(
      xnorm_bf, ipw_bf, BL, 2 * DI, DM, x_buf, z_buf, DI, nullptr, nullptr);
  // 4. causal conv + silu -> u_buf (time-strip, register sliding window)
  conv_silu_k<<<NB * (SL / TSTRIP), 256, 0, stream>>>(x_buf, conv_w, conv_b, u_buf);
  // 5. x_proj: convert weights, split-K MFMA into partial buffers, reduce (+dtex fused)
  f2b_k<<<(DXP * DI + 255) / 256, 256, 0, stream>>>(x_projw, xpw_bf, DXP * DI);
  f2b_k<<<(DI * DR) / 256, 256, 0, stream>>>(dt_projw, dtw_bf, DI * DR);
  xproj_k<<<dim3(XNS, BL / 128), 256, 0, stream>>>(u_buf, xpw_bf, Ppart);
  xred_k<<<(BL * DXP) / 256, 256, 0, stream>>>(Ppart, xdbl, dtin_bf);
  // 6. dt_proj (MFMA, fused bias+softplus) -> dt_buf
  gemm_mfma<3><<<dim3(DI / TN, BL / TM), 256, 0, stream>>>(
      dtin_bf, dtw_bf, BL, DI, DR, dt_buf, nullptr, 0, nullptr, nullptr, dt_projb);
  // 7. chunked scan
  scan_p1<<<NB * NC * (DI / 256), 256, 0, stream>>>(dt_buf, u_buf, xdbl, A_log, Pbuf, Qbuf);
  scan_p2<<<NB * DS * (DI / 256), 256, 0, stream>>>(Pbuf, Qbuf);
  scan_p3<<<NB * NC * (DI / 256), 256, 0, stream>>>(dt_buf, u_buf, xdbl, A_log, Dp, z_buf, Qbuf);
  // 8. out_proj weights -> bf16, out_proj (256x128 pipelined, full grid) + residual
  f2b_k<<<(DM * DI) / 256, 256, 0, stream>>>(out_projw, opw_bf, DM * DI);
  gemm_np<2><<<(BL / 256) * (DM / 128), 512, 0, stream>>>(
      u_buf, opw_bf, BL, DM, DI, nullptr, nullptr, 0, out, x);
}

// Round 8
// 431.638 us; speedup vs baseline: 1.1660x; 1.0003x over previous
//
#include <hip/hip_runtime.h>
#include <hip/hip_bf16.h>
#include <math.h>

#define DM 1024   // d_model
#define DI 2048   // d_inner
#define DS 16     // d_state
#define DC 4      // d_conv
#define DR 64     // dt_rank
#define NB 4      // batch
#define SL 2048   // seqlen
#define BL (NB * SL)        // 8192 rows
#define DXP (DR + 2 * DS)   // 96
#define NC 32               // scan chunks
#define CL (SL / NC)        // 64 steps per chunk
#define XNS 8               // x_proj K-splits (partial buffers, no atomics)

typedef __hip_bfloat16 bf16;
typedef __attribute__((ext_vector_type(8))) short short8;
typedef __attribute__((ext_vector_type(4))) float floatx4;
typedef unsigned int u32;

__device__ __forceinline__ float to_f(float v) { return v; }
__device__ __forceinline__ float to_f(bf16 v) { return __bfloat162float(v); }
template <typename T> __device__ __forceinline__ T from_f(float v);
template <> __device__ __forceinline__ float from_f<float>(float v) { return v; }
template <> __device__ __forceinline__ bf16 from_f<bf16>(float v) { return __float2bfloat16(v); }

__device__ __forceinline__ float bfbits2f(unsigned short u) {
  u32 b = ((u32)u) << 16;
  return __builtin_bit_cast(float, b);
}
__device__ __forceinline__ ushort f2bfbits(float v) {
  bf16 b = __float2bfloat16(v);
  return (ushort)__builtin_bit_cast(short, b);
}
// fast silu: x * rcp(1+e^-x)  (v_rcp_f32, ~1 ulp — fine for bf16 outputs)
__device__ __forceinline__ float fsilu(float v) {
  return v * __builtin_amdgcn_rcpf(1.f + __expf(-v));
}

// async global->LDS, 16B per lane. LDS dest = wave-uniform base + lane*16.
__device__ __forceinline__ void gload16(const ushort* g, ushort* l) {
  __builtin_amdgcn_global_load_lds((const __attribute__((address_space(1))) void*)g,
                                   (__attribute__((address_space(3))) void*)l,
                                   16, 0, 0);
}

__device__ __forceinline__ void vmw6() { asm volatile("s_waitcnt vmcnt(6)" ::: "memory"); }
__device__ __forceinline__ void vmw4() { asm volatile("s_waitcnt vmcnt(4)" ::: "memory"); }
__device__ __forceinline__ void vmw2() { asm volatile("s_waitcnt vmcnt(2)" ::: "memory"); }
__device__ __forceinline__ void vmw0() { asm volatile("s_waitcnt vmcnt(0)" ::: "memory"); }
// raw barrier (NO implicit vmcnt drain) with compiler-only memory fences so
// LDS reads/stages can't migrate across phases.
__device__ __forceinline__ void barx() {
  asm volatile("" ::: "memory");
  __builtin_amdgcn_s_barrier();
  asm volatile("" ::: "memory");
}

// ---------------- fp32 -> bf16 conversion ----------------
__global__ __launch_bounds__(256) void f2b_k(const float* __restrict__ src,
                                             bf16* __restrict__ dst, int n) {
  int i = blockIdx.x * 256 + threadIdx.x;
  if (i < n) dst[i] = from_f<bf16>(src[i]);
}

// ---------------- RMSNorm (bf16 out, float4 one-pass) ----------------
__global__ __launch_bounds__(256) void rmsnorm_k(const float* __restrict__ x,
                                                 const float* __restrict__ w,
                                                 bf16* __restrict__ o) {
  int row = blockIdx.x;
  const float4* xr = (const float4*)(x + (size_t)row * DM);
  float4 v = xr[threadIdx.x];          // DM = 1024 = 256 threads * 4
  float ss = v.x * v.x + v.y * v.y + v.z * v.z + v.w * v.w;
  for (int off = 32; off > 0; off >>= 1) ss += __shfl_down(ss, off);
  __shared__ float sred[4];
  __shared__ float sscale;
  if ((threadIdx.x & 63) == 0) sred[threadIdx.x >> 6] = ss;
  __syncthreads();
  if (threadIdx.x == 0) {
    float t = sred[0] + sred[1] + sred[2] + sred[3];
    sscale = rsqrtf(t / (float)DM + 1.1920929e-7f);
  }
  __syncthreads();
  float sc = sscale;
  float4 wv = ((const float4*)w)[threadIdx.x];
  ushort4 pk;
  pk.x = f2bfbits(v.x * sc * wv.x);
  pk.y = f2bfbits(v.y * sc * wv.y);
  pk.z = f2bfbits(v.z * sc * wv.z);
  pk.w = f2bfbits(v.w * sc * wv.w);
  ((ushort4*)((ushort*)o + (size_t)row * DM))[threadIdx.x] = pk;
}

// ======== 256x256 8-phase pipelined MFMA GEMM (in_proj) ========
// st_16x32 LDS swizzle (T2), half-tile prefetch + counted vmcnt (T3+T4),
// setprio (T5), N-fastest XCD swizzle, operand-swapped MFMA epilogue.
// R8: BALANCED phase reads 8/4/8/4 (was 12/4/8/0) — MM(1,0) moved to q2 so
// bq0 dies there; q3 pre-reads NEXT tile's B.n0 into bq0 from the other
// buffer.  Cross-wave certification of B(t+1): vmcnt(6) BEFORE q2's closing
// barrier (retires the 4 oldest = B(t+1) loads), barrier makes it global.
// q3-end keeps vmcnt(4)+barrier certifying A(t+1) for next q0.
template <int MODE>
__global__ __launch_bounds__(512, 1) void gemm256(const bf16* __restrict__ A,
                                                  const bf16* __restrict__ W,
                                                  int M, int N, int K,
                                                  bf16* __restrict__ Cx,
                                                  bf16* __restrict__ Cz, int nsplit,
                                                  float* __restrict__ Cf,
                                                  const float* __restrict__ R) {
  __shared__ ushort SH[65536];   // 128 KiB: A @ 0..64K, B @ 64K..128K (bytes)
  const int tid = threadIdx.x;
  const int lane = tid & 63, wv = tid >> 6;
  const int wr = wv >> 2, wc = wv & 3;
  const int row15 = lane & 15, quad = lane >> 4;

  // XCD-aware block swizzle, N-fastest within each XCD chunk
  int ntm = M >> 8, ntn = N >> 8, nwg = ntm * ntn;
  int bid = blockIdx.x;
  int swz = (bid & 7) * (nwg >> 3) + (bid >> 3);
  int bm0 = (swz / ntn) << 8, bn0 = (swz % ntn) << 8;

  const int nt = K >> 6;   // K-tiles (>= 2)
  const ushort* Au = (const ushort*)A;
  const ushort* Wu = (const ushort*)W;

  // staging: lane's inverse-swizzled source chunk (involution in chunk space)
  const int w4u = lane ^ (((lane >> 5) & 1) << 1);
  // fragment-read swizzled byte offset within a 1024B subtile
  const int Wsw = (((row15 << 6) | (quad << 4)) ^ (((row15 >> 3) & 1) << 5));
  const char* SHb = (const char*)SH;
  // ds_read base byte offsets (cur encoded in the two variants)
  const int Abase0 = (wr << 14) + Wsw;
  const int Abase1 = 32768 + (wr << 14) + Wsw;
  const int Bbase0 = 65536 + ((wc >> 1) << 14) + ((wc & 1) << 13) + Wsw;
  const int Bbase1 = Bbase0 + 32768;

  auto stageA = [&](int tt, int half, int buf) {
    const ushort* g = Au + (size_t)(bm0 + half * 128) * K + tt * 64;
    char* lds = (char*)SH + (size_t)(buf * 2 + half) * 16384;
#pragma unroll
    for (int i = 0; i < 2; ++i) {
      int sub = wv + i * 8;
      int r = ((sub >> 1) << 4) | (w4u >> 2);
      int ce = ((sub & 1) << 5) | ((w4u & 3) << 3);
      gload16(g + (size_t)r * K + ce, (ushort*)(lds + sub * 1024));
    }
  };
  auto stageB = [&](int tt, int half, int buf) {
    const ushort* g = Wu + (size_t)(bn0 + half * 128) * K + tt * 64;
    char* lds = (char*)SH + 65536 + (size_t)(buf * 2 + half) * 16384;
#pragma unroll
    for (int i = 0; i < 2; ++i) {
      int sub = wv + i * 8;
      int r = ((sub >> 1) << 4) | (w4u >> 2);
      int ce = ((sub & 1) << 5) | ((w4u & 3) << 3);
      gload16(g + (size_t)r * K + ce, (ushort*)(lds + sub * 1024));
    }
  };

  short8 a_f[4][2], bq[2][2][2];   // bq[0] = n0 (primed in prologue / prev q3)
  floatx4 acc[8][4] = {};

#define LDA_(base, mh) do { _Pragma("unroll") for (int mi = 0; mi < 4; ++mi) \
  { _Pragma("unroll") for (int kk = 0; kk < 2; ++kk) \
    a_f[mi][kk] = *(const short8*)(SHb + (base) + ((((mh)*4 + mi)*2 + kk) << 10)); } } while (0)
#define LDB_(base, nh) do { _Pragma("unroll") for (int ni = 0; ni < 2; ++ni) \
  { _Pragma("unroll") for (int kk = 0; kk < 2; ++kk) \
    bq[nh][ni][kk] = *(const short8*)(SHb + (base) + (((((nh)*2 + ni)*2 + kk)) << 10)); } } while (0)
// operand-swapped: lane&15 -> output ROW, quad*4+reg -> output COL
#define MM_(mh, nh) do { __builtin_amdgcn_s_setprio(1); \
  _Pragma("unroll") for (int mi = 0; mi < 4; ++mi) \
  { _Pragma("unroll") for (int ni = 0; ni < 2; ++ni) \
    { _Pragma("unroll") for (int kk = 0; kk < 2; ++kk) \
      acc[(mh)*4+mi][(nh)*2+ni] = __builtin_amdgcn_mfma_f32_16x16x32_bf16( \
          bq[nh][ni][kk], a_f[mi][kk], acc[(mh)*4+mi][(nh)*2+ni], 0, 0, 0); } } \
  __builtin_amdgcn_s_setprio(0); } while (0)

#define TILE_(t, AB, BB, BBn, curbuf, nxtbuf) do { \
  int tp1 = (t) + 1, tp2 = (t) + 2; \
  /* q0: a_f <- A(t).m0 (8 reads) */ \
  LDA_(AB, 0); \
  if (tp1 < nt) stageA(tp1, 0, nxtbuf); \
  barx(); MM_(0, 0); barx(); \
  /* q1: bq1 <- B(t).n1 (4 reads) */ \
  LDB_(BB, 1); \
  if (tp1 < nt) stageA(tp1, 1, nxtbuf); \
  barx(); MM_(0, 1); barx(); \
  /* q2: a_f <- A(t).m1 (8 reads); certify B(t+1) before closing barrier */ \
  LDA_(AB, 1); \
  if (tp2 < nt) stageB(tp2, 0, curbuf); \
  barx(); MM_(1, 0); \
  if (tp1 < nt) { if (tp2 < nt) vmw6(); else vmw4(); } \
  barx(); \
  /* q3: bq0 <- B(t+1).n0 (4 reads, other buffer, certified above) */ \
  if (tp1 < nt) LDB_(BBn, 0); \
  if (tp2 < nt) stageB(tp2, 1, curbuf); \
  barx(); MM_(1, 1); \
  if (tp2 < nt) vmw4(); else vmw0(); \
  barx(); \
} while (0)

  // prologue: tile0's 4 halves + tile1's B halves (12 loads)
  stageB(0, 0, 0); stageB(0, 1, 0); stageA(0, 0, 0); stageA(0, 1, 0);
  stageB(1, 0, 1); stageB(1, 1, 1);
  vmw4();   // retires B(0)+A(0); B(1)'s 4 loads stay in flight
  barx();
  LDB_(Bbase0, 0);   // prime bq0 = B(0).n0

  for (int t = 0; t < nt; t += 2) {
    TILE_(t,     Abase0, Bbase0, Bbase1, 0, 1);
    TILE_(t + 1, Abase1, Bbase1, Bbase0, 1, 0);
  }
#undef TILE_
#undef MM_
#undef LDB_
#undef LDA_

  // epilogue (swapped layout): lane owns row (.. + row15), cols (.. + quad*4 + 0..3)
#pragma unroll
  for (int mi8 = 0; mi8 < 8; ++mi8) {
    int grow = bm0 + wr * 128 + mi8 * 16 + row15;
#pragma unroll
    for (int ni4 = 0; ni4 < 4; ++ni4) {
      int gc = bn0 + wc * 64 + ni4 * 16 + quad * 4;
      floatx4 v = acc[mi8][ni4];
      if (MODE == 1) {
        if (gc < nsplit) {
          ushort4 pk = {f2bfbits(v[0]), f2bfbits(v[1]), f2bfbits(v[2]), f2bfbits(v[3])};
          *(ushort4*)((ushort*)Cx + (size_t)grow * DI + gc) = pk;
        } else {
          ushort4 pk = {f2bfbits(fsilu(v[0])), f2bfbits(fsilu(v[1])),
                        f2bfbits(fsilu(v[2])), f2bfbits(fsilu(v[3]))};
          *(ushort4*)((ushort*)Cz + (size_t)grow * DI + (gc - nsplit)) = pk;
        }
      } else {
        size_t o = (size_t)grow * N + gc;
        float4 r4 = *(const float4*)&R[o];
        float4 o4 = {v[0] + r4.x, v[1] + r4.y, v[2] + r4.z, v[3] + r4.w};
        *(float4*)&Cf[o] = o4;
      }
    }
  }
}

// ======== 256x128 pipelined MFMA GEMM (out_proj; full grid at N=1024) ====
// 8 waves (4M x 2N), fragment pre-read pipeline; LDS 96 KiB; N-fastest XCD
// swizzle; operand-swapped MFMA -> float4 C stores + float4 R loads.
template <int MODE>
__global__ __launch_bounds__(512, 1) void gemm_np(const bf16* __restrict__ A,
                                                  const bf16* __restrict__ W,
                                                  int M, int N, int K,
                                                  bf16* __restrict__ Cx,
                                                  bf16* __restrict__ Cz, int nsplit,
                                                  float* __restrict__ Cf,
                                                  const float* __restrict__ R) {
  __shared__ ushort SH[49152];   // 96 KiB
  const int tid = threadIdx.x;
  const int lane = tid & 63, wv = tid >> 6;
  const int wr = wv >> 1, wc = wv & 1;          // 4M x 2N wave grid
  const int row15 = lane & 15, quad = lane >> 4;

  // XCD-aware block swizzle, N-fastest within each XCD chunk
  int ntm = M >> 8, ntn = N >> 7, nwg = ntm * ntn;
  int bid = blockIdx.x;
  int swz = (bid & 7) * (nwg >> 3) + (bid >> 3);
  int bm0 = (swz / ntn) << 8, bn0 = (swz % ntn) << 7;

  const int nt = K >> 6;   // K-tiles (even)
  const ushort* Au = (const ushort*)A;
  const ushort* Wu = (const ushort*)W;
  const ushort* Ag = Au + (u32)bm0 * (u32)K;
  const ushort* Bg = Wu + (u32)bn0 * (u32)K;

  // staging coords: lane's inverse-swizzled chunk (st_16x32 involution)
  const int w4u = lane ^ (((lane >> 5) & 1) << 1);
  const int sub0 = wv, sub1 = wv + 8;
  const int r0 = ((sub0 >> 1) << 4) | (w4u >> 2);
  const int c0 = ((sub0 & 1) << 5) | ((w4u & 3) << 3);
  const int r1 = ((sub1 >> 1) << 4) | (w4u >> 2);
  const int c1 = ((sub1 & 1) << 5) | ((w4u & 3) << 3);
  ushort* shA = (ushort*)SH;            // 2 bufs x 16384 ushorts
  ushort* shB = (ushort*)SH + 32768;    // 2 bufs x 8192 ushorts

  auto stage = [&](const ushort* gbase, int rowoff, int tt, ushort* lbase) {
    gload16(gbase + (u32)(rowoff + r0) * (u32)K + (u32)(tt * 64 + c0), lbase + (sub0 << 9));
    gload16(gbase + (u32)(rowoff + r1) * (u32)K + (u32)(tt * 64 + c1), lbase + (sub1 << 9));
  };

  // fragment-read swizzled byte offset within a 1024B subtile
  const int Wsw = (((row15 << 6) | (quad << 4)) ^ (((row15 >> 3) & 1) << 5));
  const char* SHb = (const char*)SH;
  const int AB0 = (wr << 13) + Wsw;
  const int AB1 = 32768 + AB0;
  const int BB0 = 65536 + (wc << 13) + Wsw;
  const int BB1 = BB0 + 16384;

  short8 a0[2][2], a1[2][2], bq0A[2][2], bq0B[2][2], bq1[2][2];
  floatx4 acc[4][4] = {};

#define LDA_(dst, base, mh) do { _Pragma("unroll") for (int i_ = 0; i_ < 2; ++i_) \
  { _Pragma("unroll") for (int kk = 0; kk < 2; ++kk) \
    dst[i_][kk] = *(const short8*)(SHb + (base) + ((((mh)*2 + i_)*2 + kk) << 10)); } } while (0)
#define LDB_(dst, base, nh) do { _Pragma("unroll") for (int j_ = 0; j_ < 2; ++j_) \
  { _Pragma("unroll") for (int kk = 0; kk < 2; ++kk) \
    dst[j_][kk] = *(const short8*)(SHb + (base) + ((((nh)*2 + j_)*2 + kk) << 10)); } } while (0)
// operand-swapped
#define MM_(aset, bset, mh, nh) do { __builtin_amdgcn_s_setprio(1); \
  _Pragma("unroll") for (int i_ = 0; i_ < 2; ++i_) \
  { _Pragma("unroll") for (int j_ = 0; j_ < 2; ++j_) \
    { _Pragma("unroll") for (int kk = 0; kk < 2; ++kk) \
      acc[(mh)*2+i_][(nh)*2+j_] = __builtin_amdgcn_mfma_f32_16x16x32_bf16( \
          bset[j_][kk], aset[i_][kk], acc[(mh)*2+i_][(nh)*2+j_], 0, 0, 0); } } \
  __builtin_amdgcn_s_setprio(0); } while (0)

#define TILE_(t, ABc, BBc, ABn, BBn, BQU, BQF, CURB, NXTB) do { \
  int tp1 = (t) + 1, tp2 = (t) + 2; \
  /* q0 */ \
  LDB_(bq1, BBc, 1); \
  if (tp1 < nt) stage(Ag, 0, tp1, shA + (NXTB) * 16384); \
  barx(); MM_(a0, BQU, 0, 0); barx(); \
  /* q1 */ \
  LDA_(a1, ABc, 1); \
  if (tp1 < nt) stage(Ag, 128, tp1, shA + (NXTB) * 16384 + 8192); \
  barx(); MM_(a0, bq1, 0, 1); barx(); \
  /* q2 */ \
  if (tp2 < nt) stage(Bg, 0, tp2, shB + (CURB) * 8192); \
  barx(); MM_(a1, bq1, 1, 1); \
  if (tp2 < nt) vmw2(); else vmw0(); \
  barx(); \
  /* q3 */ \
  if (tp1 < nt) { LDA_(a0, ABn, 0); LDB_(BQF, BBn, 0); } \
  barx(); MM_(a1, BQU, 1, 0); barx(); \
} while (0)

  // prologue: B(0), A(0)-lo, A(0)-hi -> buf0 ; B(1) -> buf1
  stage(Bg, 0, 0, shB);
  stage(Ag, 0, 0, shA);
  stage(Ag, 128, 0, shA + 8192);
  if (nt > 1) { stage(Bg, 0, 1, shB + 8192); vmw2(); } else { vmw0(); }
  barx();
  LDA_(a0, AB0, 0);
  LDB_(bq0A, BB0, 0);

  for (int t = 0; t < nt; t += 2) {
    TILE_(t,     AB0, BB0, AB1, BB1, bq0A, bq0B, 0, 1);
    TILE_(t + 1, AB1, BB1, AB0, BB0, bq0B, bq0A, 1, 0);
  }
#undef TILE_
#undef MM_
#undef LDB_
#undef LDA_

  // epilogue (swapped layout)
#pragma unroll
  for (int mi = 0; mi < 4; ++mi) {
    int grow = bm0 + wr * 64 + mi * 16 + row15;
#pragma unroll
    for (int ni = 0; ni < 4; ++ni) {
      int gc = bn0 + wc * 64 + ni * 16 + quad * 4;
      floatx4 v = acc[mi][ni];
      if (MODE == 1) {
        if (gc < nsplit) {
          ushort4 pk = {f2bfbits(v[0]), f2bfbits(v[1]), f2bfbits(v[2]), f2bfbits(v[3])};
          *(ushort4*)((ushort*)Cx + (size_t)grow * DI + gc) = pk;
        } else {
          ushort4 pk = {f2bfbits(fsilu(v[0])), f2bfbits(fsilu(v[1])),
                        f2bfbits(fsilu(v[2])), f2bfbits(fsilu(v[3]))};
          *(ushort4*)((ushort*)Cz + (size_t)grow * DI + (gc - nsplit)) = pk;
        }
      } else {
        size_t o = (size_t)grow * N + gc;
        float4 r4 = *(const float4*)&R[o];
        float4 o4 = {v[0] + r4.x, v[1] + r4.y, v[2] + r4.z, v[3] + r4.w};
        *(float4*)&Cf[o] = o4;
      }
    }
  }
}

// ======== 128x128 MFMA GEMM (dt_proj, K=64) — operand-swapped epilogue ========
#define TM 128
#define TN 128
#define TK 32
#define LDK 40
template <int MODE>
__global__ __launch_bounds__(256) void gemm_mfma(const bf16* __restrict__ A,
                                                 const bf16* __restrict__ W,
                                                 int M, int N, int K,
                                                 bf16* __restrict__ Cx,
                                                 bf16* __restrict__ Cz, int nsplit,
                                                 float* __restrict__ Cf,
                                                 const float* __restrict__ R,
                                                 const float* __restrict__ bias) {
  __shared__ ushort Asm[TM][TK];   // linear — required by global_load_lds
  __shared__ ushort Bsm[TN][TK];
  int bm = blockIdx.y * TM, bn = blockIdx.x * TN;
  int tid = threadIdx.x;
  int lane = tid & 63, wave = tid >> 6;
  int wm = (wave & 1) * 64, wn = (wave >> 1) * 64;
  int row15 = lane & 15, quad = lane >> 4;

  int srow = lane >> 2;          // 0..15
  int scol = (lane & 3) * 8;     // 0,8,16,24
  int s0 = wave * 2, s1 = wave * 2 + 1;

  const ushort* Au = (const ushort*)A;
  const ushort* Wu = (const ushort*)W;
  const ushort* ag0 = Au + (size_t)(bm + s0 * 16 + srow) * K + scol;
  const ushort* ag1 = Au + (size_t)(bm + s1 * 16 + srow) * K + scol;
  const ushort* bg0 = Wu + (size_t)(bn + s0 * 16 + srow) * K + scol;
  const ushort* bg1 = Wu + (size_t)(bn + s1 * 16 + srow) * K + scol;
  ushort* la0 = &Asm[s0 * 16][0];
  ushort* la1 = &Asm[s1 * 16][0];
  ushort* lb0 = &Bsm[s0 * 16][0];
  ushort* lb1 = &Bsm[s1 * 16][0];

  floatx4 acc[4][4] = {};

  for (int k0 = 0; k0 < K; k0 += TK) {
    gload16(ag0 + k0, la0);
    gload16(ag1 + k0, la1);
    gload16(bg0 + k0, lb0);
    gload16(bg1 + k0, lb1);
    __syncthreads();
    short8 a_f[4], b_f[4];
#pragma unroll
    for (int i = 0; i < 4; ++i)
      a_f[i] = *(const short8*)&Asm[wm + i * 16 + row15][quad * 8];
#pragma unroll
    for (int j = 0; j < 4; ++j)
      b_f[j] = *(const short8*)&Bsm[wn + j * 16 + row15][quad * 8];
#pragma unroll
    for (int i = 0; i < 4; ++i)
#pragma unroll
      for (int j = 0; j < 4; ++j)
        acc[i][j] = __builtin_amdgcn_mfma_f32_16x16x32_bf16(b_f[j], a_f[i], acc[i][j], 0, 0, 0);
    __syncthreads();
  }
  // swapped epilogue: lane owns row (..+row15), cols (..+quad*4+0..3)
#pragma unroll
  for (int mi = 0; mi < 4; ++mi) {
    int grow = bm + wm + mi * 16 + row15;
#pragma unroll
    for (int ni = 0; ni < 4; ++ni) {
      int gc = bn + wn + ni * 16 + quad * 4;
      floatx4 v = acc[mi][ni];
      if (MODE == 1) {
        if (gc < nsplit) {
          ushort4 pk = {f2bfbits(v[0]), f2bfbits(v[1]), f2bfbits(v[2]), f2bfbits(v[3])};
          *(ushort4*)((ushort*)Cx + (size_t)grow * DI + gc) = pk;
        } else {
          ushort4 pk = {f2bfbits(fsilu(v[0])), f2bfbits(fsilu(v[1])),
                        f2bfbits(fsilu(v[2])), f2bfbits(fsilu(v[3]))};
          *(ushort4*)((ushort*)Cz + (size_t)grow * DI + (gc - nsplit)) = pk;
        }
      } else if (MODE == 2) {
        size_t o = (size_t)grow * N + gc;
        float4 r4 = *(const float4*)&R[o];
        float4 o4 = {v[0] + r4.x, v[1] + r4.y, v[2] + r4.z, v[3] + r4.w};
        *(float4*)&Cf[o] = o4;
      } else {  // MODE 3: dt softplus, packed
        float4 b4 = *(const float4*)&bias[gc];
        float t0 = v[0] + b4.x, t1 = v[1] + b4.y, t2 = v[2] + b4.z, t3 = v[3] + b4.w;
        float s0_ = (t0 > 20.f) ? t0 : __logf(1.f + __expf(t0));
        float s1_ = (t1 > 20.f) ? t1 : __logf(1.f + __expf(t1));
        float s2_ = (t2 > 20.f) ? t2 : __logf(1.f + __expf(t2));
        float s3_ = (t3 > 20.f) ? t3 : __logf(1.f + __expf(t3));
        ushort4 pk = {f2bfbits(s0_), f2bfbits(s1_), f2bfbits(s2_), f2bfbits(s3_)};
        *(ushort4*)((ushort*)Cx + (size_t)grow * N + gc) = pk;
      }
    }
  }
}

// ======== x_proj split-K MFMA, partial buffers (no atomics, swapped epilogue) ====
__global__ __launch_bounds__(256) void xproj_k(const bf16* __restrict__ u,
                                               const bf16* __restrict__ w,
                                               float* __restrict__ Ppart) {
  __shared__ ushort Asm[128][LDK];
  __shared__ ushort Bsm[96][LDK];
  int kbase = blockIdx.x * (DI / XNS);
  int bm = blockIdx.y * 128;
  int tid = threadIdx.x;
  int lane = tid & 63, wave = tid >> 6;
  int row15 = lane & 15, quad = lane >> 4;
  int srow = tid >> 1, skoff = (tid & 1) * 16;

  floatx4 acc[2][6] = {};
  const ushort* Au = (const ushort*)u;
  const ushort* Wu = (const ushort*)w;
  for (int k0 = kbase; k0 < kbase + (DI / XNS); k0 += TK) {
    const ushort* ag = Au + (size_t)(bm + srow) * DI + k0 + skoff;
    *(short8*)&Asm[srow][skoff]     = *(const short8*)ag;
    *(short8*)&Asm[srow][skoff + 8] = *(const short8*)(ag + 8);
    if (tid < 192) {
      const ushort* wg = Wu + (size_t)srow * DI + k0 + skoff;
      *(short8*)&Bsm[srow][skoff]     = *(const short8*)wg;
      *(short8*)&Bsm[srow][skoff + 8] = *(const short8*)(wg + 8);
    }
    __syncthreads();
    short8 a_f[2], b_f[6];
#pragma unroll
    for (int i = 0; i < 2; ++i)
      a_f[i] = *(const short8*)&Asm[wave * 32 + i * 16 + row15][quad * 8];
#pragma unroll
    for (int j = 0; j < 6; ++j)
      b_f[j] = *(const short8*)&Bsm[j * 16 + row15][quad * 8];
#pragma unroll
    for (int i = 0; i < 2; ++i)
#pragma unroll
      for (int j = 0; j < 6; ++j)
        acc[i][j] = __builtin_amdgcn_mfma_f32_16x16x32_bf16(b_f[j], a_f[i], acc[i][j], 0, 0, 0);
    __syncthreads();
  }
  float* P = Ppart + (size_t)blockIdx.x * ((size_t)BL * DXP);
#pragma unroll
  for (int mi = 0; mi < 2; ++mi) {
    int grow = bm + wave * 32 + mi * 16 + row15;
#pragma unroll
    for (int nj = 0; nj < 6; ++nj) {
      int gc = nj * 16 + quad * 4;
      floatx4 v = acc[mi][nj];
      float4 o4 = {v[0], v[1], v[2], v[3]};
      *(float4*)&P[(size_t)grow * DXP + gc] = o4;
    }
  }
}

// ---- reduce partials -> xdbl fp32; also emit dtin bf16 (fuses old dtex_k) ----
__global__ __launch_bounds__(256) void xred_k(const float* __restrict__ Ppart,
                                              float* __restrict__ xdbl,
                                              bf16* __restrict__ dtin) {
  int i = blockIdx.x * 256 + threadIdx.x;   // BL * DXP total
  float s = 0.f;
#pragma unroll
  for (int p = 0; p < XNS; ++p) s += Ppart[(size_t)p * ((size_t)BL * DXP) + i];
  xdbl[i] = s;
  int r = i / DXP, c = i - r * DXP;
  if (c < DR) dtin[r * DR + c] = from_f<bf16>(s);
}

// ---------------- causal depthwise conv (K=4) + SiLU ----------------
#define TSTRIP 8
__global__ __launch_bounds__(256) void conv_silu_k(const bf16* __restrict__ xin,
                                                   const float* __restrict__ cw,
                                                   const float* __restrict__ cb,
                                                   bf16* __restrict__ u) {
  int blk = blockIdx.x;                   // NB * (SL/TSTRIP) blocks
  int b = blk >> 8;
  int l0 = (blk & 255) * TSTRIP;
  int c0 = threadIdx.x * 8;

  float4 cw4[8];
  const float4* cwp = (const float4*)cw;
#pragma unroll
  for (int j = 0; j < 8; ++j) cw4[j] = cwp[c0 + j];
  float cbv[8];
  {
    float4 cb0 = *(const float4*)&cb[c0];
    float4 cb1 = *(const float4*)&cb[c0 + 4];
    cbv[0] = cb0.x; cbv[1] = cb0.y; cbv[2] = cb0.z; cbv[3] = cb0.w;
    cbv[4] = cb1.x; cbv[5] = cb1.y; cbv[6] = cb1.z; cbv[7] = cb1.w;
  }

  const ushort* base = (const ushort*)xin + ((size_t)(b * SL + l0) * DI + c0);
  ushort* ubase = (ushort*)u + ((size_t)(b * SL + l0) * DI + c0);

  short8 zz = {};
  short8 w0 = zz, w1 = zz, w2 = zz;
  if (l0 >= 3) {
    w0 = *(const short8*)(base - 3 * DI);
    w1 = *(const short8*)(base - 2 * DI);
    w2 = *(const short8*)(base - 1 * DI);
  }
#pragma unroll
  for (int l = 0; l < TSTRIP; ++l) {
    short8 w3 = *(const short8*)(base + (ptrdiff_t)l * DI);
    short8 outv;
#pragma unroll
    for (int j = 0; j < 8; ++j) {
      float a = cbv[j]
              + bfbits2f((unsigned short)w0[j]) * cw4[j].x
              + bfbits2f((unsigned short)w1[j]) * cw4[j].y
              + bfbits2f((unsigned short)w2[j]) * cw4[j].z
              + bfbits2f((unsigned short)w3[j]) * cw4[j].w;
      outv[j] = (short)f2bfbits(fsilu(a));
    }
    *(short8*)(ubase + (ptrdiff_t)l * DI) = outv;
    w0 = w1; w1 = w2; w2 = w3;
  }
}

// ======== chunked selective scan ========
__global__ __launch_bounds__(256) void scan_p1(const bf16* __restrict__ dts,
                                               const bf16* __restrict__ u,
                                               const float* __restrict__ xdbl,
                                               const float* __restrict__ A_log,
                                               float* __restrict__ Pbuf,
                                               float* __restrict__ Qbuf) {
  int bid = blockIdx.x;
  int b = bid >> 8;
  int c = (bid >> 3) & (NC - 1);
  int d = (bid & 7) * 256 + threadIdx.x;

  float A[DS], h[DS], P[DS];
#pragma unroll
  for (int s = 0; s < DS; ++s) {
    A[s] = -__expf(A_log[d * DS + s]);
    h[s] = 0.f; P[s] = 1.f;
  }
  size_t bl0 = (size_t)b * SL + c * CL;
  size_t base = bl0 * DI + d;
  size_t xb = bl0 * DXP + DR;
  for (int l = 0; l < CL; ++l) {
    float dtv = to_f(dts[base]);
    float uv = to_f(u[base]);
    float du = dtv * uv;
    float Bv[16];
    *(float4*)&Bv[0]  = *(const float4*)(xdbl + xb);
    *(float4*)&Bv[4]  = *(const float4*)(xdbl + xb + 4);
    *(float4*)&Bv[8]  = *(const float4*)(xdbl + xb + 8);
    *(float4*)&Bv[12] = *(const float4*)(xdbl + xb + 12);
#pragma unroll
    for (int s = 0; s < DS; ++s) {
      float dA = __expf(dtv * A[s]);
      h[s] = dA * h[s] + du * Bv[s];
      P[s] *= dA;
    }
    base += DI;
    xb += DXP;
  }
  size_t o = ((size_t)(b * NC + c) * DS) * DI + d;
#pragma unroll
  for (int s = 0; s < DS; ++s) {
    Pbuf[o + (size_t)s * DI] = P[s];
    Qbuf[o + (size_t)s * DI] = h[s];
  }
}

__global__ __launch_bounds__(256) void scan_p2(float* __restrict__ Pbuf,
                                               float* __restrict__ Qbuf) {
  int bid = blockIdx.x;
  int b = bid >> 7;
  int s = (bid >> 3) & (DS - 1);
  int d = (bid & 7) * 256 + threadIdx.x;
  float h = 0.f;
  for (int c = 0; c < NC; ++c) {
    size_t idx = ((size_t)((b * NC + c) * DS + s)) * DI + d;
    float Pv = Pbuf[idx];
    float qv = Qbuf[idx];
    Qbuf[idx] = h;
    h = Pv * h + qv;
  }
}

__global__ __launch_bounds__(256) void scan_p3(const bf16* __restrict__ dts,
                                               bf16* __restrict__ u,
                                               const float* __restrict__ xdbl,
                                               const float* __restrict__ A_log,
                                               const float* __restrict__ Dp,
                                               const bf16* __restrict__ g,
                                               const float* __restrict__ Qbuf) {
  int bid = blockIdx.x;
  int b = bid >> 8;
  int c = (bid >> 3) & (NC - 1);
  int d = (bid & 7) * 256 + threadIdx.x;

  float A[DS], h[DS];
  size_t o = ((size_t)(b * NC + c) * DS) * DI + d;
#pragma unroll
  for (int s = 0; s < DS; ++s) {
    A[s] = -__expf(A_log[d * DS + s]);
    h[s] = Qbuf[o + (size_t)s * DI];
  }
  float Dd = Dp[d];
  size_t bl0 = (size_t)b * SL + c * CL;
  size_t base = bl0 * DI + d;
  size_t xb = bl0 * DXP + DR;
  for (int l = 0; l < CL; ++l) {
    float dtv = to_f(dts[base]);
    float uv = to_f(u[base]);
    float gv = to_f(g[base]);
    float du = dtv * uv;
    float Bv[16], Cv[16];
    *(float4*)&Bv[0]  = *(const float4*)(xdbl + xb);
    *(float4*)&Bv[4]  = *(const float4*)(xdbl + xb + 4);
    *(float4*)&Bv[8]  = *(const float4*)(xdbl + xb + 8);
    *(float4*)&Bv[12] = *(const float4*)(xdbl + xb + 12);
    *(float4*)&Cv[0]  = *(const float4*)(xdbl + xb + DS);
    *(float4*)&Cv[4]  = *(const float4*)(xdbl + xb + DS + 4);
    *(float4*)&Cv[8]  = *(const float4*)(xdbl + xb + DS + 8);
    *(float4*)&Cv[12] = *(const float4*)(xdbl + xb + DS + 12);
    float p0 = 0.f, p1 = 0.f, p2 = 0.f, p3 = 0.f;
#pragma unroll
    for (int s = 0; s < DS; s += 4) {
      float dA0 = __expf(dtv * A[s + 0]);
      float dA1 = __expf(dtv * A[s + 1]);
      float dA2 = __expf(dtv * A[s + 2]);
      float dA3 = __expf(dtv * A[s + 3]);
      h[s + 0] = dA0 * h[s + 0] + du * Bv[s + 0];
      h[s + 1] = dA1 * h[s + 1] + du * Bv[s + 1];
      h[s + 2] = dA2 * h[s + 2] + du * Bv[s + 2];
      h[s + 3] = dA3 * h[s + 3] + du * Bv[s + 3];
      p0 += h[s + 0] * Cv[s + 0];
      p1 += h[s + 1] * Cv[s + 1];
      p2 += h[s + 2] * Cv[s + 2];
      p3 += h[s + 3] * Cv[s + 3];
    }
    float yv = ((p0 + p1) + (p2 + p3)) + Dd * uv;
    u[base] = from_f<bf16>(yv * gv);
    base += DI;
    xb += DXP;
  }
}

extern "C" void kernel_launch(void* const* d_in, const int* in_sizes, int n_in,
                              void* d_out, int out_size, void* d_ws, size_t ws_size,
                              hipStream_t stream) {
  const float* x        = (const float*)d_in[0];
  const float* norm_w   = (const float*)d_in[1];
  const float* in_projw = (const float*)d_in[2];
  const float* conv_w   = (const float*)d_in[3];
  const float* conv_b   = (const float*)d_in[4];
  const float* x_projw  = (const float*)d_in[5];
  const float* dt_projw = (const float*)d_in[6];
  const float* dt_projb = (const float*)d_in[7];
  const float* A_log    = (const float*)d_in[8];
  const float* Dp       = (const float*)d_in[9];
  const float* out_projw= (const float*)d_in[10];
  float* out = (float*)d_out;

  // ---- workspace (~104 MiB), lifetime overlays ----
  char* wsb = (char*)d_ws;
  bf16* x_buf  = (bf16*)wsb;                           // x half; later dt; later opw_bf
  bf16* z_buf  = (bf16*)(wsb + (size_t)BL * DI * 2);   // silu(z) gate
  bf16* u_buf  = (bf16*)(wsb + (size_t)BL * DI * 4);   // xnorm_bf (early) then u/y
  char* ovl    = wsb + (size_t)BL * DI * 6;            // 8 MiB overlay
  bf16* ipw_bf = (bf16*)ovl;                           // phase A: in_proj w bf16 (8 MiB)
  // phase B overlay (after in_proj):
  float* xdbl   = (float*)ovl;                                 // 3 MiB
  bf16*  xpw_bf = (bf16*)(ovl + 3145728);                      // 0.375 MiB
  bf16*  dtw_bf = (bf16*)(ovl + 3538944);                      // 0.25 MiB
  bf16*  dtin_bf= (bf16*)(ovl + 3801088);                      // 1 MiB
  bf16* xnorm_bf = u_buf;
  bf16* dt_buf   = x_buf;   // x half dead after conv
  bf16* opw_bf   = x_buf;   // dt dead after scan p3
  float* Ppart = out;       // d_out scratch: xproj partials (24 MiB), dead after xred
  float* Pbuf = out;        // d_out scratch until out_proj
  float* Qbuf = out + (size_t)NB * NC * DS * DI;

  // 1. in_proj weights -> bf16
  f2b_k<<<(2 * DI * DM) / 256, 256, 0, stream>>>(in_projw, ipw_bf, 2 * DI * DM);
  // 2. RMSNorm -> bf16
  rmsnorm_k<<<BL, 256, 0, stream>>>(x, norm_w, xnorm_bf);
  // 3. in_proj (256x256 8-phase MFMA): x half -> x_buf ; z half silu -> z_buf
  gemm256<1><<<(BL / 256) * (2 * DI / 256), 512, 0, stream>>>(
      xnorm_bf, ipw_bf, BL, 2 * DI, DM, x_buf, z_buf, DI, nullptr, nullptr);
  // 4. causal conv + silu -> u_buf (time-strip, register sliding window)
  conv_silu_k<<<NB * (SL / TSTRIP), 256, 0, stream>>>(x_buf, conv_w, conv_b, u_buf);
  // 5. x_proj: convert weights, split-K MFMA into partial buffers, reduce (+dtex fused)
  f2b_k<<<(DXP * DI + 255) / 256, 256, 0, stream>>>(x_projw, xpw_bf, DXP * DI);
  f2b_k<<<(DI * DR) / 256, 256, 0, stream>>>(dt_projw, dtw_bf, DI * DR);
  xproj_k<<<dim3(XNS, BL / 128), 256, 0, stream>>>(u_buf, xpw_bf, Ppart);
  xred_k<<<(BL * DXP) / 256, 256, 0, stream>>>(Ppart, xdbl, dtin_bf);
  // 6. dt_proj (MFMA, fused bias+softplus) -> dt_buf
  gemm_mfma<3><<<dim3(DI / TN, BL / TM), 256, 0, stream>>>(
      dtin_bf, dtw_bf, BL, DI, DR, dt_buf, nullptr, 0, nullptr, nullptr, dt_projb);
  // 7. chunked scan
  scan_p1<<<NB * NC * (DI / 256), 256, 0, stream>>>(dt_buf, u_buf, xdbl, A_log, Pbuf, Qbuf);
  scan_p2<<<NB * DS * (DI / 256), 256, 0, stream>>>(Pbuf, Qbuf);
  scan_p3<<<NB * NC * (DI / 256), 256, 0, stream>>>(dt_buf, u_buf, xdbl, A_log, Dp, z_buf, Qbuf);
  // 8. out_proj weights -> bf16, out_proj (256x128 pipelined, full grid) + residual
  f2b_k<<<(DM * DI) / 256, 256, 0, stream>>>(out_projw, opw_bf, DM * DI);
  gemm_np<2><<<(BL / 256) * (DM / 128), 512, 0, stream>>>(
      u_buf, opw_bf, BL, DM, DI, nullptr, nullptr, 0, out, x);
}